// Round 8
// baseline (277.722 us; speedup 1.0000x reference)
//
#include <hip/hip_runtime.h>
#include <hip/hip_bf16.h>

#define NHEAD 8
#define DK_ 64
#define DM_ 512
#define S_LEN 4096
#define NTOK 8192

typedef __bf16 bf16x8 __attribute__((ext_vector_type(8)));
typedef float f32x4 __attribute__((ext_vector_type(4)));
typedef float f32x16 __attribute__((ext_vector_type(16)));
typedef unsigned int uint4v __attribute__((ext_vector_type(4)));

__device__ __forceinline__ unsigned short f2bf(float f) {
    union { float f; unsigned u; } x; x.f = f;
    unsigned u = x.u;
    u += 0x7FFFu + ((u >> 16) & 1u);   // round-to-nearest-even (inputs finite)
    return (unsigned short)(u >> 16);
}

// packed f32x2 -> bf16x2 (gfx950 HW op when available; RNE either way)
#if __has_builtin(__builtin_amdgcn_cvt_pk_bf16_f32)
__device__ __forceinline__ unsigned int pkbf(float a, float b) {
    auto r = __builtin_amdgcn_cvt_pk_bf16_f32(a, b);
    unsigned int u; __builtin_memcpy(&u, &r, 4); return u;
}
#else
__device__ __forceinline__ unsigned int pkbf(float a, float b) {
    return (unsigned)f2bf(a) | ((unsigned)f2bf(b) << 16);
}
#endif

#if __has_builtin(__builtin_amdgcn_exp2f)
#define EXP2F(x) __builtin_amdgcn_exp2f(x)
#else
#define EXP2F(x) exp2f(x)
#endif

// lane-half <-> reg exchange: new_a = {a_lo, b_lo}, new_b = {a_hi, b_hi}
#if __has_builtin(__builtin_amdgcn_permlane32_swap)
__device__ __forceinline__ void pl32swap(unsigned int& a, unsigned int& b) {
    auto r = __builtin_amdgcn_permlane32_swap(a, b, false, false);
    a = r[0]; b = r[1];
}
#else
__device__ __forceinline__ void pl32swap(unsigned int& a, unsigned int& b) {
    int lane = threadIdx.x & 63;
    unsigned int ax = __shfl_xor((int)a, 32, 64);
    unsigned int bx = __shfl_xor((int)b, 32, 64);
    unsigned int na = (lane < 32) ? a : bx;
    unsigned int nb = (lane < 32) ? ax : b;
    a = na; b = nb;
}
#endif

// async global->LDS, 16B per lane; LDS dest = wave-uniform base + lane*16
#define GLOAD_LDS16(gptr, ldsbase) \
    __builtin_amdgcn_global_load_lds((const __attribute__((address_space(1))) unsigned int*)(gptr), \
                                     (__attribute__((address_space(3))) unsigned int*)(ldsbase), 16, 0, 0)

// ---------- prep: fused xcvt (z<3) + wtrans (z==3) -> one launch ----------
__global__ __launch_bounds__(256) void prep(const float* __restrict__ q, const float* __restrict__ k,
                                            const float* __restrict__ v,
                                            const float* __restrict__ Wq, const float* __restrict__ Wk,
                                            const float* __restrict__ Wv, const float* __restrict__ Wo,
                                            unsigned short* __restrict__ Xbf, unsigned short* __restrict__ Wt) {
    __shared__ float t[64][65];
    int z = blockIdx.y;
    int tid = threadIdx.x;
    if (z < 3) {
        const float* X = (z == 0) ? q : (z == 1) ? k : v;
        size_t off = (size_t)blockIdx.x * 1024 + tid * 4;
        float4 val = *(const float4*)&X[off];
        uint2 o; o.x = pkbf(val.x, val.y); o.y = pkbf(val.z, val.w);
        *(uint2*)&Xbf[(size_t)z * NTOK * DM_ + off] = o;
        return;
    }
    int bi = blockIdx.x;
    if (bi >= 256) return;
    int zz = bi >> 6;
    int bn = (bi & 7) * 64, bk = ((bi >> 3) & 7) * 64;
    const float* W = (zz == 0) ? Wq : (zz == 1) ? Wk : (zz == 2) ? Wv : Wo;
    unsigned short* out = Wt + (size_t)zz * DM_ * DM_;
    int r0 = tid >> 4, c4 = (tid & 15) * 4;
#pragma unroll
    for (int i = 0; i < 4; i++) {
        int r = r0 + i * 16;
        float4 vv = *(const float4*)&W[(size_t)(bk + r) * DM_ + bn + c4];
        t[r][c4] = vv.x; t[r][c4 + 1] = vv.y; t[r][c4 + 2] = vv.z; t[r][c4 + 3] = vv.w;
    }
    __syncthreads();
    int n0 = tid >> 4, k4 = (tid & 15) * 4;
#pragma unroll
    for (int i = 0; i < 4; i++) {
        int n = n0 + i * 16;
        ushort4 o;
        o.x = f2bf(t[k4 + 0][n]); o.y = f2bf(t[k4 + 1][n]);
        o.z = f2bf(t[k4 + 2][n]); o.w = f2bf(t[k4 + 3][n]);
        *(ushort4*)&out[(size_t)(bn + n) * DM_ + bk + k4] = o;
    }
}

// ---------- standalone wtrans (smallest-ws fallback path) ----------
__global__ __launch_bounds__(256) void wtrans(const float* __restrict__ Wq, const float* __restrict__ Wk,
                                              const float* __restrict__ Wv, const float* __restrict__ Wo,
                                              unsigned short* __restrict__ Wt) {
    int z = blockIdx.z;
    const float* W = (z == 0) ? Wq : (z == 1) ? Wk : (z == 2) ? Wv : Wo;
    unsigned short* out = Wt + (size_t)z * DM_ * DM_;
    __shared__ float t[64][65];
    int bn = blockIdx.x * 64, bk = blockIdx.y * 64;
    int tid = threadIdx.x;
    int r0 = tid >> 4, c4 = (tid & 15) * 4;
#pragma unroll
    for (int i = 0; i < 4; i++) {
        int r = r0 + i * 16;
        float4 v = *(const float4*)&W[(size_t)(bk + r) * DM_ + bn + c4];
        t[r][c4] = v.x; t[r][c4 + 1] = v.y; t[r][c4 + 2] = v.z; t[r][c4 + 3] = v.w;
    }
    __syncthreads();
    int n0 = tid >> 4, k4 = (tid & 15) * 4;
#pragma unroll
    for (int i = 0; i < 4; i++) {
        int n = n0 + i * 16;
        ushort4 o;
        o.x = f2bf(t[k4 + 0][n]); o.y = f2bf(t[k4 + 1][n]);
        o.z = f2bf(t[k4 + 2][n]); o.w = f2bf(t[k4 + 3][n]);
        *(ushort4*)&out[(size_t)(bn + n) * DM_ + bk + k4] = o;
    }
}

// shared epilogue for projection GEMMs (original orientation; used by fallback)
__device__ __forceinline__ void proj_epilogue(int z, f32x4 (&acc)[4][4], const float* bias,
                                              unsigned short* out, float scale,
                                              int m0, int n0, int mb, int nb, int ln, int qd) {
    float bvv[4];
#pragma unroll
    for (int nt = 0; nt < 4; nt++) bvv[nt] = bias[n0 + nb + nt * 16 + ln];
#pragma unroll
    for (int mt = 0; mt < 4; mt++) {
        int mrow0 = m0 + mb + mt * 16 + qd * 4;
        int b = mrow0 >> 12, s = mrow0 & 4095;
#pragma unroll
        for (int nt = 0; nt < 4; nt++) {
            int ncol = n0 + nb + nt * 16 + ln;
            int h = ncol >> 6, d = ncol & 63;
            if (z == 2) {
                uint2 o;
                o.x = pkbf((acc[mt][nt][0] + bvv[nt]) * scale, (acc[mt][nt][1] + bvv[nt]) * scale);
                o.y = pkbf((acc[mt][nt][2] + bvv[nt]) * scale, (acc[mt][nt][3] + bvv[nt]) * scale);
                *(uint2*)&out[((size_t)(b * NHEAD + h) * DK_ + d) * S_LEN + s] = o;
            } else {
#pragma unroll
                for (int r = 0; r < 4; r++)
                    out[((size_t)(b * NHEAD + h) * S_LEN + (s + r)) * DK_ + d] =
                        f2bf((acc[mt][nt][r] + bvv[nt]) * scale);
            }
        }
    }
}

// ---------- fused QKV projection, LDS-DMA staged, transposed-acc epilogue ----------
// r7 post-mortem: z<2 epilogue was 64 SCALAR 2-byte stores/thread (~350 VALU
// ops) — a large issue-bound cost invisible in top-5 counters. Fix: for z<2
// swap MFMA operands (mfma(bf,af) -> acc holds C^T; A/B fragment layouts are
// symmetric, same trick as flash's S^T). Register index then walks the FEATURE
// dim: each thread holds 4 consecutive d for one token -> 16 packed ushort4
// stores (2x pkbf each) + float4 bias loads. z==2 keeps original orientation
// (already packed for the [d][s] layout).
__global__ __launch_bounds__(256, 3) void qkv_bf(const unsigned short* __restrict__ Xbf,
                                                 const unsigned short* __restrict__ Wt,
                                                 const float* __restrict__ bq, const float* __restrict__ bk,
                                                 const float* __restrict__ bv,
                                                 unsigned short* __restrict__ Qh, unsigned short* __restrict__ Kh,
                                                 unsigned short* __restrict__ VhT) {
    int z = blockIdx.z;
    const unsigned short* X = Xbf + (size_t)z * NTOK * DM_;
    const unsigned short* W = Wt + (size_t)z * DM_ * DM_;
    const float* bias = (z == 0) ? bq : (z == 1) ? bk : bv;
    unsigned short* out = (z == 0) ? Qh : (z == 1) ? Kh : VhT;
    float scale = (z == 0) ? 0.125f * 1.44269504f : 1.0f;

    __shared__ unsigned short As[128 * 32];
    __shared__ unsigned short Bs[128 * 32];
    int tid = threadIdx.x;
    int n0 = blockIdx.x * 128, m0 = blockIdx.y * 128;
    int w = tid >> 6, lane = tid & 63;
    int ln = lane & 15, qd = lane >> 4;
    int mb = (w >> 1) * 64, nb = (w & 1) * 64;

    int lr = lane >> 2;                              // local row 0..15
    int cs = ((lane & 3) ^ (lr & 3)) * 8;            // pre-swizzled source chunk (elems)
    int rdc = (qd ^ (ln & 3)) * 8;                   // swizzled read chunk (elems)

    f32x4 acc[4][4];
#pragma unroll
    for (int i = 0; i < 4; i++)
#pragma unroll
        for (int j = 0; j < 4; j++) { f32x4 zz = {0.f, 0.f, 0.f, 0.f}; acc[i][j] = zz; }

    for (int kk = 0; kk < DM_; kk += 32) {
        __syncthreads();
#pragma unroll
        for (int j = 0; j < 2; j++) {
            int r0 = w * 32 + j * 16;
            GLOAD_LDS16(&X[(size_t)(m0 + r0 + lr) * DM_ + kk + cs], &As[r0 * 32]);
            GLOAD_LDS16(&W[(size_t)(n0 + r0 + lr) * DM_ + kk + cs], &Bs[r0 * 32]);
        }
        __syncthreads();
        bf16x8 af[4], bf[4];
#pragma unroll
        for (int mt = 0; mt < 4; mt++) af[mt] = *(const bf16x8*)&As[(mb + mt * 16 + ln) * 32 + rdc];
#pragma unroll
        for (int nt = 0; nt < 4; nt++) bf[nt] = *(const bf16x8*)&Bs[(nb + nt * 16 + ln) * 32 + rdc];
        if (z < 2) {
            // transposed product: acc[mt][nt] = W-rows x X-rows^T (C^T layout)
#pragma unroll
            for (int mt = 0; mt < 4; mt++)
#pragma unroll
                for (int nt = 0; nt < 4; nt++)
                    acc[mt][nt] = __builtin_amdgcn_mfma_f32_16x16x32_bf16(bf[nt], af[mt], acc[mt][nt], 0, 0, 0);
        } else {
#pragma unroll
            for (int mt = 0; mt < 4; mt++)
#pragma unroll
                for (int nt = 0; nt < 4; nt++)
                    acc[mt][nt] = __builtin_amdgcn_mfma_f32_16x16x32_bf16(af[mt], bf[nt], acc[mt][nt], 0, 0, 0);
        }
    }

    if (z < 2) {
        // C^T: reg j = feature d offset (qd*4+j), col ln = token offset
#pragma unroll
        for (int nt = 0; nt < 4; nt++) {
            int d0 = n0 + nb + nt * 16 + qd * 4;       // 4-aligned, within one head
            int h = d0 >> 6, dl = d0 & 63;
            float4 b4 = *(const float4*)&bias[d0];
#pragma unroll
            for (int mt = 0; mt < 4; mt++) {
                int token = m0 + mb + mt * 16 + ln;
                int b = token >> 12, s = token & 4095;
                uint2 o;
                o.x = pkbf((acc[mt][nt][0] + b4.x) * scale, (acc[mt][nt][1] + b4.y) * scale);
                o.y = pkbf((acc[mt][nt][2] + b4.z) * scale, (acc[mt][nt][3] + b4.w) * scale);
                *(uint2*)&out[((size_t)(b * NHEAD + h) * S_LEN + s) * DK_ + dl] = o;
            }
        }
    } else {
        // V: original orientation; pack token-pairs into the [d][s] layout
        float bvv[4];
#pragma unroll
        for (int nt = 0; nt < 4; nt++) bvv[nt] = bias[n0 + nb + nt * 16 + ln];
#pragma unroll
        for (int mt = 0; mt < 4; mt++) {
            int mrow0 = m0 + mb + mt * 16 + qd * 4;
            int b = mrow0 >> 12, s = mrow0 & 4095;
#pragma unroll
            for (int nt = 0; nt < 4; nt++) {
                int ncol = n0 + nb + nt * 16 + ln;
                int h = ncol >> 6, d = ncol & 63;
                uint2 o;
                o.x = pkbf(acc[mt][nt][0] + bvv[nt], acc[mt][nt][1] + bvv[nt]);
                o.y = pkbf(acc[mt][nt][2] + bvv[nt], acc[mt][nt][3] + bvv[nt]);
                *(uint2*)&out[((size_t)(b * NHEAD + h) * DK_ + d) * S_LEN + s] = o;
            }
        }
    }
}

// ---------- fallback fused QKV projection from fp32 X (small ws) ----------
__global__ __launch_bounds__(256, 3) void qkv_proj(const float* __restrict__ xq, const float* __restrict__ xk,
                                                   const float* __restrict__ xv, const unsigned short* __restrict__ Wt,
                                                   const float* __restrict__ bq, const float* __restrict__ bk,
                                                   const float* __restrict__ bv,
                                                   unsigned short* __restrict__ Qh, unsigned short* __restrict__ Kh,
                                                   unsigned short* __restrict__ VhT) {
    int z = blockIdx.z;
    const float* X = (z == 0) ? xq : (z == 1) ? xk : xv;
    const unsigned short* W = Wt + (size_t)z * DM_ * DM_;
    const float* bias = (z == 0) ? bq : (z == 1) ? bk : bv;
    unsigned short* out = (z == 0) ? Qh : (z == 1) ? Kh : VhT;
    float scale = (z == 0) ? 0.125f * 1.44269504f : 1.0f;

    __shared__ unsigned short As[128 * 40];
    __shared__ unsigned short Bs[128 * 40];
    int tid = threadIdx.x;
    int n0 = blockIdx.x * 128, m0 = blockIdx.y * 128;
    int w = tid >> 6, lane = tid & 63;
    int ln = lane & 15, qd = lane >> 4;
    int mb = (w >> 1) * 64, nb = (w & 1) * 64;

    f32x4 acc[4][4];
#pragma unroll
    for (int i = 0; i < 4; i++)
#pragma unroll
        for (int j = 0; j < 4; j++) { f32x4 zz = {0.f, 0.f, 0.f, 0.f}; acc[i][j] = zz; }

    for (int kk = 0; kk < DM_; kk += 32) {
        __syncthreads();
#pragma unroll
        for (int i = 0; i < 4; i++) {
            int idx = i * 256 + tid;
            int row = idx >> 3, k4 = (idx & 7) * 4;
            float4 v = *(const float4*)&X[(size_t)(m0 + row) * DM_ + kk + k4];
            uint2 o; o.x = pkbf(v.x, v.y); o.y = pkbf(v.z, v.w);
            *(uint2*)&As[row * 40 + k4] = o;
        }
#pragma unroll
        for (int i = 0; i < 2; i++) {
            int idx = i * 256 + tid;
            int row = idx >> 2, k8 = (idx & 3) * 8;
            uint4 v = *(const uint4*)&W[(size_t)(n0 + row) * DM_ + kk + k8];
            *(uint4*)&Bs[row * 40 + k8] = v;
        }
        __syncthreads();
        bf16x8 af[4], bf[4];
#pragma unroll
        for (int mt = 0; mt < 4; mt++) af[mt] = *(const bf16x8*)&As[(mb + mt * 16 + ln) * 40 + qd * 8];
#pragma unroll
        for (int nt = 0; nt < 4; nt++) bf[nt] = *(const bf16x8*)&Bs[(nb + nt * 16 + ln) * 40 + qd * 8];
#pragma unroll
        for (int mt = 0; mt < 4; mt++)
#pragma unroll
            for (int nt = 0; nt < 4; nt++)
                acc[mt][nt] = __builtin_amdgcn_mfma_f32_16x16x32_bf16(af[mt], bf[nt], acc[mt][nt], 0, 0, 0);
    }
    proj_epilogue(z, acc, bias, out, scale, m0, n0, mb, nb, ln, qd);
}

// ---------- flash attention (legacy single-pass, small-ws fallback) ----------
__global__ __launch_bounds__(256, 2) void flash_attn(const unsigned short* __restrict__ Qh,
                                                     const unsigned short* __restrict__ Kh,
                                                     const unsigned short* __restrict__ VhT,
                                                     unsigned short* __restrict__ Ao) {
    __shared__ unsigned short Ks[2][64 * 64];     // 16 KB
    __shared__ unsigned short Vs[2][64 * 64];     // 16 KB
    int i = blockIdx.x;
    int bh = (i & 7) + 8 * ((i >> 3) & 1);
    int qb = i >> 4;
    int tid = threadIdx.x;
    int w = tid >> 6, lane = tid & 63;
    int ln = lane & 31, hf = lane >> 5;
    int swz = ln & 7;
    int q0 = qb * 128 + w * 32;
    const unsigned short* Qp = Qh + (size_t)bh * S_LEN * DK_;
    const unsigned short* Kp = Kh + (size_t)bh * S_LEN * DK_;
    const unsigned short* Vp = VhT + (size_t)bh * DK_ * S_LEN;

    int sr = lane >> 3;
    int sc = (lane & 7) ^ sr;
    const unsigned short* ksrc = Kp + (size_t)(w * 16 + sr) * DK_ + sc * 8;
    const unsigned short* vsrc = Vp + (size_t)(w * 16 + sr) * S_LEN + sc * 8;

    bf16x8 qf[4];
#pragma unroll
    for (int s = 0; s < 4; s++)
        qf[s] = *(const bf16x8*)&Qp[(size_t)(q0 + ln) * DK_ + s * 16 + hf * 8];

    f32x16 oacc[2];
    { f32x16 z = {0.f}; oacc[0] = z; oacc[1] = z; }
    float lsum = 0.f;

    GLOAD_LDS16(ksrc, &Ks[0][w * 1024]);
    GLOAD_LDS16(ksrc + (size_t)8 * DK_, &Ks[0][w * 1024 + 512]);
    GLOAD_LDS16(vsrc, &Vs[0][w * 1024]);
    GLOAD_LDS16(vsrc + (size_t)8 * S_LEN, &Vs[0][w * 1024 + 512]);

    int p = 0;
    for (int ks = 0; ks < S_LEN; ks += 64, p ^= 1) {
        __syncthreads();
        if (ks + 64 < S_LEN) {
            const unsigned short* kn = ksrc + (size_t)(ks + 64) * DK_;
            const unsigned short* vn = vsrc + (ks + 64);
            GLOAD_LDS16(kn, &Ks[p ^ 1][w * 1024]);
            GLOAD_LDS16(kn + (size_t)8 * DK_, &Ks[p ^ 1][w * 1024 + 512]);
            GLOAD_LDS16(vn, &Vs[p ^ 1][w * 1024]);
            GLOAD_LDS16(vn + (size_t)8 * S_LEN, &Vs[p ^ 1][w * 1024 + 512]);
        }
        const unsigned short* KsT = &Ks[p][0];
        const unsigned short* VsT = &Vs[p][0];

#pragma unroll
        for (int kb = 0; kb < 2; kb++) {
            f32x16 st = {0.f};
#pragma unroll
            for (int s = 0; s < 4; s++) {
                bf16x8 kf = *(const bf16x8*)&KsT[(kb * 32 + ln) * 64 + ((2 * s + hf) ^ swz) * 8];
                st = __builtin_amdgcn_mfma_f32_32x32x16_bf16(kf, qf[s], st, 0, 0, 0);
            }
            float e[16];
#pragma unroll
            for (int r = 0; r < 16; r++) e[r] = EXP2F(st[r]);
            lsum += ((e[0] + e[1]) + (e[2] + e[3])) + ((e[4] + e[5]) + (e[6] + e[7]))
                  + ((e[8] + e[9]) + (e[10] + e[11])) + ((e[12] + e[13]) + (e[14] + e[15]));
            unsigned int g[8];
#pragma unroll
            for (int gi = 0; gi < 8; gi++) g[gi] = pkbf(e[2 * gi], e[2 * gi + 1]);
            pl32swap(g[0], g[2]); pl32swap(g[1], g[3]);
            pl32swap(g[4], g[6]); pl32swap(g[5], g[7]);
            bf16x8 b0, b1;
            { uint4v t = {g[0], g[1], g[2], g[3]}; __builtin_memcpy(&b0, &t, 16); }
            { uint4v t = {g[4], g[5], g[6], g[7]}; __builtin_memcpy(&b1, &t, 16); }
#pragma unroll
            for (int dt = 0; dt < 2; dt++) {
                int s0 = kb * 2;
                bf16x8 vf0 = *(const bf16x8*)&VsT[(dt * 32 + ln) * 64 + ((2 * s0 + hf) ^ swz) * 8];
                bf16x8 vf1 = *(const bf16x8*)&VsT[(dt * 32 + ln) * 64 + ((2 * s0 + 2 + hf) ^ swz) * 8];
                oacc[dt] = __builtin_amdgcn_mfma_f32_32x32x16_bf16(vf0, b0, oacc[dt], 0, 0, 0);
                oacc[dt] = __builtin_amdgcn_mfma_f32_32x32x16_bf16(vf1, b1, oacc[dt], 0, 0, 0);
            }
        }
    }

    float ltot = lsum + __shfl_xor(lsum, 32, 64);
    float inv = 1.0f / ltot;

    int bb = bh >> 3, hh = bh & 7;
    int token = bb * S_LEN + q0 + ln;
#pragma unroll
    for (int dt = 0; dt < 2; dt++)
#pragma unroll
        for (int gi = 0; gi < 8; gi++) {
            int d = dt * 32 + 2 * (gi & 1) + 8 * (gi >> 1) + 4 * hf;
            unsigned int o = pkbf(oacc[dt][2 * gi] * inv, oacc[dt][2 * gi + 1] * inv);
            *(unsigned int*)&Ao[(size_t)token * DM_ + hh * DK_ + d] = o;
        }
}

// ---------- fused split-K flash: 2 key-teams in ONE block, merge in LDS ----------
__global__ __launch_bounds__(512, 4) void flash_attn_f(const unsigned short* __restrict__ Qh,
                                                       const unsigned short* __restrict__ Kh,
                                                       const unsigned short* __restrict__ VhT,
                                                       unsigned short* __restrict__ Ao) {
    __shared__ __align__(16) unsigned char smem[65536];
    int i = blockIdx.x;
    int bh = i & 15;
    int qb = i >> 4;                               // 0..31
    int tid = threadIdx.x;
    int w = tid >> 6, lane = tid & 63;
    int team = w >> 2, wl = w & 3;
    int ln = lane & 31, hf = lane >> 5;
    int swz = ln & 7;
    int q0 = qb * 128 + wl * 32;
    int ks0 = team * (S_LEN / 2);
    int ks1 = ks0 + (S_LEN / 2);
    const unsigned short* Qp = Qh + (size_t)bh * S_LEN * DK_;
    const unsigned short* Kp = Kh + (size_t)bh * S_LEN * DK_;
    const unsigned short* Vp = VhT + (size_t)bh * DK_ * S_LEN;

    // per-team LDS: Ks[2][64*64] at team*32768, Vs[2][64*64] at +16384
    unsigned short* KsB = (unsigned short*)(smem + team * 32768);
    unsigned short* VsB = (unsigned short*)(smem + team * 32768 + 16384);

    int sr = lane >> 3;
    int sc = (lane & 7) ^ sr;
    const unsigned short* ksrc = Kp + (size_t)(wl * 16 + sr) * DK_ + sc * 8;
    const unsigned short* vsrc = Vp + (size_t)(wl * 16 + sr) * S_LEN + sc * 8;

    bf16x8 qf[4];
#pragma unroll
    for (int s = 0; s < 4; s++)
        qf[s] = *(const bf16x8*)&Qp[(size_t)(q0 + ln) * DK_ + s * 16 + hf * 8];

    f32x16 oacc[2];
    { f32x16 z = {0.f}; oacc[0] = z; oacc[1] = z; }
    float lsum = 0.f;

    GLOAD_LDS16(ksrc + (size_t)ks0 * DK_, &KsB[wl * 1024]);
    GLOAD_LDS16(ksrc + (size_t)(ks0 + 8) * DK_, &KsB[wl * 1024 + 512]);
    GLOAD_LDS16(vsrc + ks0, &VsB[wl * 1024]);
    GLOAD_LDS16(vsrc + ks0 + (size_t)8 * S_LEN, &VsB[wl * 1024 + 512]);

    int p = 0;
    for (int ks = ks0; ks < ks1; ks += 64, p ^= 1) {
        __syncthreads();   // drains DMA for buf p; all waves done reading buf p^1
        if (ks + 64 < ks1) {
            const unsigned short* kn = ksrc + (size_t)(ks + 64) * DK_;
            const unsigned short* vn = vsrc + (ks + 64);
            GLOAD_LDS16(kn, &KsB[(p ^ 1) * 4096 + wl * 1024]);
            GLOAD_LDS16(kn + (size_t)8 * DK_, &KsB[(p ^ 1) * 4096 + wl * 1024 + 512]);
            GLOAD_LDS16(vn, &VsB[(p ^ 1) * 4096 + wl * 1024]);
            GLOAD_LDS16(vn + (size_t)8 * S_LEN, &VsB[(p ^ 1) * 4096 + wl * 1024 + 512]);
        }
        const unsigned short* KsT = &KsB[p * 4096];
        const unsigned short* VsT = &VsB[p * 4096];

#pragma unroll
        for (int kb = 0; kb < 2; kb++) {
            f32x16 st = {0.f};
#pragma unroll
            for (int s = 0; s < 4; s++) {
                bf16x8 kf = *(const bf16x8*)&KsT[(kb * 32 + ln) * 64 + ((2 * s + hf) ^ swz) * 8];
                st = __builtin_amdgcn_mfma_f32_32x32x16_bf16(kf, qf[s], st, 0, 0, 0);
            }
            float e[16];
#pragma unroll
            for (int r = 0; r < 16; r++) e[r] = EXP2F(st[r]);
            lsum += ((e[0] + e[1]) + (e[2] + e[3])) + ((e[4] + e[5]) + (e[6] + e[7]))
                  + ((e[8] + e[9]) + (e[10] + e[11])) + ((e[12] + e[13]) + (e[14] + e[15]));
            unsigned int g[8];
#pragma unroll
            for (int gi = 0; gi < 8; gi++) g[gi] = pkbf(e[2 * gi], e[2 * gi + 1]);
            pl32swap(g[0], g[2]); pl32swap(g[1], g[3]);
            pl32swap(g[4], g[6]); pl32swap(g[5], g[7]);
            bf16x8 b0, b1;
            { uint4v t = {g[0], g[1], g[2], g[3]}; __builtin_memcpy(&b0, &t, 16); }
            { uint4v t = {g[4], g[5], g[6], g[7]}; __builtin_memcpy(&b1, &t, 16); }
#pragma unroll
            for (int dt = 0; dt < 2; dt++) {
                int s0 = kb * 2;
                bf16x8 vf0 = *(const bf16x8*)&VsT[(dt * 32 + ln) * 64 + ((2 * s0 + hf) ^ swz) * 8];
                bf16x8 vf1 = *(const bf16x8*)&VsT[(dt * 32 + ln) * 64 + ((2 * s0 + 2 + hf) ^ swz) * 8];
                oacc[dt] = __builtin_amdgcn_mfma_f32_32x32x16_bf16(vf0, b0, oacc[dt], 0, 0, 0);
                oacc[dt] = __builtin_amdgcn_mfma_f32_32x32x16_bf16(vf1, b1, oacc[dt], 0, 0, 0);
            }
        }
    }

    // per-team denominator (both lane-halves combined)
    float ltot = lsum + __shfl_xor(lsum, 32, 64);

    // ---- cross-team merge in LDS (K/V buffers are dead) ----
    __syncthreads();
    float* eps = (float*)smem;          // 8192 f32 = 32KB (team-0's region)
    float* epl = eps + 8192;            // 128 f32 for lsums (team-1's region)
    if (team == 1) {
#pragma unroll
        for (int dt = 0; dt < 2; dt++)
#pragma unroll
            for (int r = 0; r < 16; r++)
                eps[wl * 2048 + dt * 1024 + r * 64 + lane] = oacc[dt][r];
        if (hf == 0) epl[wl * 32 + ln] = ltot;
    }
    __syncthreads();
    if (team == 0) {
#pragma unroll
        for (int dt = 0; dt < 2; dt++)
#pragma unroll
            for (int r = 0; r < 16; r++)
                oacc[dt][r] += eps[wl * 2048 + dt * 1024 + r * 64 + lane];
        float inv = 1.0f / (ltot + epl[wl * 32 + ln]);

        int bb = bh >> 3, hh = bh & 7;
        int token = bb * S_LEN + q0 + ln;
#pragma unroll
        for (int dt = 0; dt < 2; dt++)
#pragma unroll
            for (int gi = 0; gi < 8; gi++) {
                int d = dt * 32 + 2 * (gi & 1) + 8 * (gi >> 1) + 4 * hf;
                unsigned int o = pkbf(oacc[dt][2 * gi] * inv, oacc[dt][2 * gi + 1] * inv);
                *(unsigned int*)&Ao[(size_t)token * DM_ + hh * DK_ + d] = o;
            }
    }
}

// ---------- output GEMM: out = Ao(bf16)@Wo + bo, fp32 out (LDS-DMA staged) ----------
__global__ __launch_bounds__(256, 3) void out_gemm(const unsigned short* __restrict__ A,
                                                   const unsigned short* __restrict__ Wt,
                                                   const float* __restrict__ bias, float* __restrict__ out) {
    __shared__ unsigned short As[128 * 32];
    __shared__ unsigned short Bs[128 * 32];
    int tid = threadIdx.x;
    int n0 = blockIdx.x * 128, m0 = blockIdx.y * 128;
    int w = tid >> 6, lane = tid & 63;
    int ln = lane & 15, qd = lane >> 4;
    int mb = (w >> 1) * 64, nb = (w & 1) * 64;

    int lr = lane >> 2;
    int cs = ((lane & 3) ^ (lr & 3)) * 8;
    int rdc = (qd ^ (ln & 3)) * 8;

    f32x4 acc[4][4];
#pragma unroll
    for (int i = 0; i < 4; i++)
#pragma unroll
        for (int j = 0; j < 4; j++) { f32x4 z = {0.f, 0.f, 0.f, 0.f}; acc[i][j] = z; }

    for (int kk = 0; kk < DM_; kk += 32) {
        __syncthreads();
#pragma unroll
        for (int j = 0; j < 2; j++) {
            int r0 = w * 32 + j * 16;
            GLOAD_LDS16(&A[(size_t)(m0 + r0 + lr) * DM_ + kk + cs], &As[r0 * 32]);
            GLOAD_LDS16(&Wt[(size_t)(n0 + r0 + lr) * DM_ + kk + cs], &Bs[r0 * 32]);
        }
        __syncthreads();
        bf16x8 af[4], bf[4];
#pragma unroll
        for (int mt = 0; mt < 4; mt++) af[mt] = *(const bf16x8*)&As[(mb + mt * 16 + ln) * 32 + rdc];
#pragma unroll
        for (int nt = 0; nt < 4; nt++) bf[nt] = *(const bf16x8*)&Bs[(nb + nt * 16 + ln) * 32 + rdc];
#pragma unroll
        for (int mt = 0; mt < 4; mt++)
#pragma unroll
            for (int nt = 0; nt < 4; nt++)
                acc[mt][nt] = __builtin_amdgcn_mfma_f32_16x16x32_bf16(af[mt], bf[nt], acc[mt][nt], 0, 0, 0);
    }

    float bv[4];
#pragma unroll
    for (int nt = 0; nt < 4; nt++) bv[nt] = bias[n0 + nb + nt * 16 + ln];
#pragma unroll
    for (int mt = 0; mt < 4; mt++) {
        int mrow0 = m0 + mb + mt * 16 + qd * 4;
#pragma unroll
        for (int nt = 0; nt < 4; nt++) {
            int ncol = n0 + nb + nt * 16 + ln;
#pragma unroll
            for (int r = 0; r < 4; r++)
                out[(size_t)(mrow0 + r) * DM_ + ncol] = acc[mt][nt][r] + bv[nt];
        }
    }
}

extern "C" void kernel_launch(void* const* d_in, const int* in_sizes, int n_in,
                              void* d_out, int out_size, void* d_ws, size_t ws_size,
                              hipStream_t stream) {
    const float* q  = (const float*)d_in[0];
    const float* k  = (const float*)d_in[1];
    const float* v  = (const float*)d_in[2];
    const float* Wq = (const float*)d_in[3];
    const float* bq = (const float*)d_in[4];
    const float* Wk = (const float*)d_in[5];
    const float* bk = (const float*)d_in[6];
    const float* Wv = (const float*)d_in[7];
    const float* bv = (const float*)d_in[8];
    const float* Wo = (const float*)d_in[9];
    const float* bo = (const float*)d_in[10];
    float* out = (float*)d_out;

    unsigned short* Wt  = (unsigned short*)d_ws;
    unsigned short* Qh  = Wt + (size_t)4 * DM_ * DM_;
    unsigned short* Kh  = Qh + (size_t)NTOK * DM_;
    unsigned short* VhT = Kh + (size_t)NTOK * DM_;
    unsigned short* tail = VhT + (size_t)NTOK * DM_;

    size_t need_bf = ((size_t)4 * DM_ * DM_ + (size_t)6 * NTOK * DM_) * 2;

    if (ws_size >= need_bf) {
        unsigned short* Xbf = tail;   // Ao aliases Xbf head (Xbf dead before flash writes Ao)
        unsigned short* Ao = tail;
        prep<<<dim3(4096, 4), 256, 0, stream>>>(q, k, v, Wq, Wk, Wv, Wo, Xbf, Wt);
        qkv_bf<<<dim3(4, 64, 3), 256, 0, stream>>>(Xbf, Wt, bq, bk, bv, Qh, Kh, VhT);
        flash_attn_f<<<dim3(512), 512, 0, stream>>>(Qh, Kh, VhT, Ao);
        out_gemm<<<dim3(4, 64), 256, 0, stream>>>(Ao, Wt + (size_t)3 * DM_ * DM_, bo, out);
    } else {
        unsigned short* Ao = tail;
        wtrans<<<dim3(8, 8, 4), 256, 0, stream>>>(Wq, Wk, Wv, Wo, Wt);
        qkv_proj<<<dim3(4, 64, 3), 256, 0, stream>>>(q, k, v, Wt, bq, bk, bv, Qh, Kh, VhT);
        flash_attn<<<dim3(512), 256, 0, stream>>>(Qh, Kh, VhT, Ao);
        out_gemm<<<dim3(4, 64), 256, 0, stream>>>(Ao, Wt + (size_t)3 * DM_ * DM_, bo, out);
    }
}

// Round 9
// 239.330 us; speedup vs baseline: 1.1604x; 1.1604x over previous
//
#include <hip/hip_runtime.h>
#include <hip/hip_bf16.h>

#define NHEAD 8
#define DK_ 64
#define DM_ 512
#define S_LEN 4096
#define NTOK 8192

typedef __bf16 bf16x8 __attribute__((ext_vector_type(8)));
typedef float f32x4 __attribute__((ext_vector_type(4)));
typedef float f32x16 __attribute__((ext_vector_type(16)));
typedef unsigned int uint4v __attribute__((ext_vector_type(4)));

__device__ __forceinline__ unsigned short f2bf(float f) {
    union { float f; unsigned u; } x; x.f = f;
    unsigned u = x.u;
    u += 0x7FFFu + ((u >> 16) & 1u);   // round-to-nearest-even (inputs finite)
    return (unsigned short)(u >> 16);
}

// packed f32x2 -> bf16x2 (gfx950 HW op when available; RNE either way)
#if __has_builtin(__builtin_amdgcn_cvt_pk_bf16_f32)
__device__ __forceinline__ unsigned int pkbf(float a, float b) {
    auto r = __builtin_amdgcn_cvt_pk_bf16_f32(a, b);
    unsigned int u; __builtin_memcpy(&u, &r, 4); return u;
}
#else
__device__ __forceinline__ unsigned int pkbf(float a, float b) {
    return (unsigned)f2bf(a) | ((unsigned)f2bf(b) << 16);
}
#endif

#if __has_builtin(__builtin_amdgcn_exp2f)
#define EXP2F(x) __builtin_amdgcn_exp2f(x)
#else
#define EXP2F(x) exp2f(x)
#endif

// lane-half <-> reg exchange: new_a = {a_lo, b_lo}, new_b = {a_hi, b_hi}
#if __has_builtin(__builtin_amdgcn_permlane32_swap)
__device__ __forceinline__ void pl32swap(unsigned int& a, unsigned int& b) {
    auto r = __builtin_amdgcn_permlane32_swap(a, b, false, false);
    a = r[0]; b = r[1];
}
#else
__device__ __forceinline__ void pl32swap(unsigned int& a, unsigned int& b) {
    int lane = threadIdx.x & 63;
    unsigned int ax = __shfl_xor((int)a, 32, 64);
    unsigned int bx = __shfl_xor((int)b, 32, 64);
    unsigned int na = (lane < 32) ? a : bx;
    unsigned int nb = (lane < 32) ? ax : b;
    a = na; b = nb;
}
#endif

// async global->LDS, 16B per lane; LDS dest = wave-uniform base + lane*16
#define GLOAD_LDS16(gptr, ldsbase) \
    __builtin_amdgcn_global_load_lds((const __attribute__((address_space(1))) unsigned int*)(gptr), \
                                     (__attribute__((address_space(3))) unsigned int*)(ldsbase), 16, 0, 0)

// ---------- prep v2: grid-stride xcvt (blocks 0..2047) + wtrans (2048..2303) ----------
// r8 decomposition: old prep was 16384 blocks (4KB of work each; 3840 no-ops)
// — 24x more dispatches than needed (Guideline 11: cap ~2048, grid-stride).
// xcvt: 2048 blocks x 256 thr x 6 float4-chunks, chunk-major stride (coalesced).
__global__ __launch_bounds__(256) void prep(const float* __restrict__ q, const float* __restrict__ k,
                                            const float* __restrict__ v,
                                            const float* __restrict__ Wq, const float* __restrict__ Wk,
                                            const float* __restrict__ Wv, const float* __restrict__ Wo,
                                            unsigned short* __restrict__ Xbf, unsigned short* __restrict__ Wt) {
    __shared__ float t[64][65];
    int bi = blockIdx.x;
    int tid = threadIdx.x;
    if (bi < 2048) {
        size_t gtid = (size_t)bi * 256 + tid;
#pragma unroll
        for (int it = 0; it < 6; it++) {
            size_t c = gtid + (size_t)it * 524288;   // chunk idx in [0, 3*NTOK*DM_/4)
            size_t e = c * 4;                        // element idx; NTOK*DM_ = 2^22
            int z = (int)(e >> 22);
            size_t off = e & 4194303u;
            const float* X = (z == 0) ? q : (z == 1) ? k : v;
            float4 val = *(const float4*)&X[off];
            uint2 o; o.x = pkbf(val.x, val.y); o.y = pkbf(val.z, val.w);
            *(uint2*)&Xbf[e] = o;
        }
        return;
    }
    int wi = bi - 2048;                              // 0..255
    int zz = wi >> 6;
    int bn = (wi & 7) * 64, bk = ((wi >> 3) & 7) * 64;
    const float* W = (zz == 0) ? Wq : (zz == 1) ? Wk : (zz == 2) ? Wv : Wo;
    unsigned short* out = Wt + (size_t)zz * DM_ * DM_;
    int r0 = tid >> 4, c4 = (tid & 15) * 4;
#pragma unroll
    for (int i = 0; i < 4; i++) {
        int r = r0 + i * 16;
        float4 vv = *(const float4*)&W[(size_t)(bk + r) * DM_ + bn + c4];
        t[r][c4] = vv.x; t[r][c4 + 1] = vv.y; t[r][c4 + 2] = vv.z; t[r][c4 + 3] = vv.w;
    }
    __syncthreads();
    int n0 = tid >> 4, k4 = (tid & 15) * 4;
#pragma unroll
    for (int i = 0; i < 4; i++) {
        int n = n0 + i * 16;
        ushort4 o;
        o.x = f2bf(t[k4 + 0][n]); o.y = f2bf(t[k4 + 1][n]);
        o.z = f2bf(t[k4 + 2][n]); o.w = f2bf(t[k4 + 3][n]);
        *(ushort4*)&out[(size_t)(bn + n) * DM_ + bk + k4] = o;
    }
}

// ---------- standalone wtrans (smallest-ws fallback path) ----------
__global__ __launch_bounds__(256) void wtrans(const float* __restrict__ Wq, const float* __restrict__ Wk,
                                              const float* __restrict__ Wv, const float* __restrict__ Wo,
                                              unsigned short* __restrict__ Wt) {
    int z = blockIdx.z;
    const float* W = (z == 0) ? Wq : (z == 1) ? Wk : (z == 2) ? Wv : Wo;
    unsigned short* out = Wt + (size_t)z * DM_ * DM_;
    __shared__ float t[64][65];
    int bn = blockIdx.x * 64, bk = blockIdx.y * 64;
    int tid = threadIdx.x;
    int r0 = tid >> 4, c4 = (tid & 15) * 4;
#pragma unroll
    for (int i = 0; i < 4; i++) {
        int r = r0 + i * 16;
        float4 v = *(const float4*)&W[(size_t)(bk + r) * DM_ + bn + c4];
        t[r][c4] = v.x; t[r][c4 + 1] = v.y; t[r][c4 + 2] = v.z; t[r][c4 + 3] = v.w;
    }
    __syncthreads();
    int n0 = tid >> 4, k4 = (tid & 15) * 4;
#pragma unroll
    for (int i = 0; i < 4; i++) {
        int n = n0 + i * 16;
        ushort4 o;
        o.x = f2bf(t[k4 + 0][n]); o.y = f2bf(t[k4 + 1][n]);
        o.z = f2bf(t[k4 + 2][n]); o.w = f2bf(t[k4 + 3][n]);
        *(ushort4*)&out[(size_t)(bn + n) * DM_ + bk + k4] = o;
    }
}

// shared epilogue for projection GEMMs
__device__ __forceinline__ void proj_epilogue(int z, f32x4 (&acc)[4][4], const float* bias,
                                              unsigned short* out, float scale,
                                              int m0, int n0, int mb, int nb, int ln, int qd) {
    float bvv[4];
#pragma unroll
    for (int nt = 0; nt < 4; nt++) bvv[nt] = bias[n0 + nb + nt * 16 + ln];
#pragma unroll
    for (int mt = 0; mt < 4; mt++) {
        int mrow0 = m0 + mb + mt * 16 + qd * 4;
        int b = mrow0 >> 12, s = mrow0 & 4095;
#pragma unroll
        for (int nt = 0; nt < 4; nt++) {
            int ncol = n0 + nb + nt * 16 + ln;
            int h = ncol >> 6, d = ncol & 63;
            if (z == 2) {
                uint2 o;
                o.x = pkbf((acc[mt][nt][0] + bvv[nt]) * scale, (acc[mt][nt][1] + bvv[nt]) * scale);
                o.y = pkbf((acc[mt][nt][2] + bvv[nt]) * scale, (acc[mt][nt][3] + bvv[nt]) * scale);
                *(uint2*)&out[((size_t)(b * NHEAD + h) * DK_ + d) * S_LEN + s] = o;
            } else {
#pragma unroll
                for (int r = 0; r < 4; r++)
                    out[((size_t)(b * NHEAD + h) * S_LEN + (s + r)) * DK_ + d] =
                        f2bf((acc[mt][nt][r] + bvv[nt]) * scale);
            }
        }
    }
}

// ---------- fused QKV projection, LDS-DMA staged (m97 pattern; r7 verbatim) ----------
// r8's C^T operand-swap epilogue regressed -37us (reverted; post-mortem rule:
// prediction didn't match -> revert, don't patch).
__global__ __launch_bounds__(256, 3) void qkv_bf(const unsigned short* __restrict__ Xbf,
                                                 const unsigned short* __restrict__ Wt,
                                                 const float* __restrict__ bq, const float* __restrict__ bk,
                                                 const float* __restrict__ bv,
                                                 unsigned short* __restrict__ Qh, unsigned short* __restrict__ Kh,
                                                 unsigned short* __restrict__ VhT) {
    int z = blockIdx.z;
    const unsigned short* X = Xbf + (size_t)z * NTOK * DM_;
    const unsigned short* W = Wt + (size_t)z * DM_ * DM_;
    const float* bias = (z == 0) ? bq : (z == 1) ? bk : bv;
    unsigned short* out = (z == 0) ? Qh : (z == 1) ? Kh : VhT;
    float scale = (z == 0) ? 0.125f * 1.44269504f : 1.0f;

    __shared__ unsigned short As[128 * 32];
    __shared__ unsigned short Bs[128 * 32];
    int tid = threadIdx.x;
    int n0 = blockIdx.x * 128, m0 = blockIdx.y * 128;
    int w = tid >> 6, lane = tid & 63;
    int ln = lane & 15, qd = lane >> 4;
    int mb = (w >> 1) * 64, nb = (w & 1) * 64;

    int lr = lane >> 2;                              // local row 0..15
    int cs = ((lane & 3) ^ (lr & 3)) * 8;            // pre-swizzled source chunk (elems)
    int rdc = (qd ^ (ln & 3)) * 8;                   // swizzled read chunk (elems)

    f32x4 acc[4][4];
#pragma unroll
    for (int i = 0; i < 4; i++)
#pragma unroll
        for (int j = 0; j < 4; j++) { f32x4 zz = {0.f, 0.f, 0.f, 0.f}; acc[i][j] = zz; }

    for (int kk = 0; kk < DM_; kk += 32) {
        __syncthreads();
#pragma unroll
        for (int j = 0; j < 2; j++) {
            int r0 = w * 32 + j * 16;
            GLOAD_LDS16(&X[(size_t)(m0 + r0 + lr) * DM_ + kk + cs], &As[r0 * 32]);
            GLOAD_LDS16(&W[(size_t)(n0 + r0 + lr) * DM_ + kk + cs], &Bs[r0 * 32]);
        }
        __syncthreads();
        bf16x8 af[4], bf[4];
#pragma unroll
        for (int mt = 0; mt < 4; mt++) af[mt] = *(const bf16x8*)&As[(mb + mt * 16 + ln) * 32 + rdc];
#pragma unroll
        for (int nt = 0; nt < 4; nt++) bf[nt] = *(const bf16x8*)&Bs[(nb + nt * 16 + ln) * 32 + rdc];
#pragma unroll
        for (int mt = 0; mt < 4; mt++)
#pragma unroll
            for (int nt = 0; nt < 4; nt++)
                acc[mt][nt] = __builtin_amdgcn_mfma_f32_16x16x32_bf16(af[mt], bf[nt], acc[mt][nt], 0, 0, 0);
    }
    proj_epilogue(z, acc, bias, out, scale, m0, n0, mb, nb, ln, qd);
}

// ---------- fallback fused QKV projection from fp32 X (small ws) ----------
__global__ __launch_bounds__(256, 3) void qkv_proj(const float* __restrict__ xq, const float* __restrict__ xk,
                                                   const float* __restrict__ xv, const unsigned short* __restrict__ Wt,
                                                   const float* __restrict__ bq, const float* __restrict__ bk,
                                                   const float* __restrict__ bv,
                                                   unsigned short* __restrict__ Qh, unsigned short* __restrict__ Kh,
                                                   unsigned short* __restrict__ VhT) {
    int z = blockIdx.z;
    const float* X = (z == 0) ? xq : (z == 1) ? xk : xv;
    const unsigned short* W = Wt + (size_t)z * DM_ * DM_;
    const float* bias = (z == 0) ? bq : (z == 1) ? bk : bv;
    unsigned short* out = (z == 0) ? Qh : (z == 1) ? Kh : VhT;
    float scale = (z == 0) ? 0.125f * 1.44269504f : 1.0f;

    __shared__ unsigned short As[128 * 40];
    __shared__ unsigned short Bs[128 * 40];
    int tid = threadIdx.x;
    int n0 = blockIdx.x * 128, m0 = blockIdx.y * 128;
    int w = tid >> 6, lane = tid & 63;
    int ln = lane & 15, qd = lane >> 4;
    int mb = (w >> 1) * 64, nb = (w & 1) * 64;

    f32x4 acc[4][4];
#pragma unroll
    for (int i = 0; i < 4; i++)
#pragma unroll
        for (int j = 0; j < 4; j++) { f32x4 zz = {0.f, 0.f, 0.f, 0.f}; acc[i][j] = zz; }

    for (int kk = 0; kk < DM_; kk += 32) {
        __syncthreads();
#pragma unroll
        for (int i = 0; i < 4; i++) {
            int idx = i * 256 + tid;
            int row = idx >> 3, k4 = (idx & 7) * 4;
            float4 v = *(const float4*)&X[(size_t)(m0 + row) * DM_ + kk + k4];
            uint2 o; o.x = pkbf(v.x, v.y); o.y = pkbf(v.z, v.w);
            *(uint2*)&As[row * 40 + k4] = o;
        }
#pragma unroll
        for (int i = 0; i < 2; i++) {
            int idx = i * 256 + tid;
            int row = idx >> 2, k8 = (idx & 3) * 8;
            uint4 v = *(const uint4*)&W[(size_t)(n0 + row) * DM_ + kk + k8];
            *(uint4*)&Bs[row * 40 + k8] = v;
        }
        __syncthreads();
        bf16x8 af[4], bf[4];
#pragma unroll
        for (int mt = 0; mt < 4; mt++) af[mt] = *(const bf16x8*)&As[(mb + mt * 16 + ln) * 40 + qd * 8];
#pragma unroll
        for (int nt = 0; nt < 4; nt++) bf[nt] = *(const bf16x8*)&Bs[(nb + nt * 16 + ln) * 40 + qd * 8];
#pragma unroll
        for (int mt = 0; mt < 4; mt++)
#pragma unroll
            for (int nt = 0; nt < 4; nt++)
                acc[mt][nt] = __builtin_amdgcn_mfma_f32_16x16x32_bf16(af[mt], bf[nt], acc[mt][nt], 0, 0, 0);
    }
    proj_epilogue(z, acc, bias, out, scale, m0, n0, mb, nb, ln, qd);
}

// ---------- flash attention (legacy single-pass, small-ws fallback) ----------
__global__ __launch_bounds__(256, 2) void flash_attn(const unsigned short* __restrict__ Qh,
                                                     const unsigned short* __restrict__ Kh,
                                                     const unsigned short* __restrict__ VhT,
                                                     unsigned short* __restrict__ Ao) {
    __shared__ unsigned short Ks[2][64 * 64];     // 16 KB
    __shared__ unsigned short Vs[2][64 * 64];     // 16 KB
    int i = blockIdx.x;
    int bh = (i & 7) + 8 * ((i >> 3) & 1);
    int qb = i >> 4;
    int tid = threadIdx.x;
    int w = tid >> 6, lane = tid & 63;
    int ln = lane & 31, hf = lane >> 5;
    int swz = ln & 7;
    int q0 = qb * 128 + w * 32;
    const unsigned short* Qp = Qh + (size_t)bh * S_LEN * DK_;
    const unsigned short* Kp = Kh + (size_t)bh * S_LEN * DK_;
    const unsigned short* Vp = VhT + (size_t)bh * DK_ * S_LEN;

    int sr = lane >> 3;
    int sc = (lane & 7) ^ sr;
    const unsigned short* ksrc = Kp + (size_t)(w * 16 + sr) * DK_ + sc * 8;
    const unsigned short* vsrc = Vp + (size_t)(w * 16 + sr) * S_LEN + sc * 8;

    bf16x8 qf[4];
#pragma unroll
    for (int s = 0; s < 4; s++)
        qf[s] = *(const bf16x8*)&Qp[(size_t)(q0 + ln) * DK_ + s * 16 + hf * 8];

    f32x16 oacc[2];
    { f32x16 z = {0.f}; oacc[0] = z; oacc[1] = z; }
    float lsum = 0.f;

    GLOAD_LDS16(ksrc, &Ks[0][w * 1024]);
    GLOAD_LDS16(ksrc + (size_t)8 * DK_, &Ks[0][w * 1024 + 512]);
    GLOAD_LDS16(vsrc, &Vs[0][w * 1024]);
    GLOAD_LDS16(vsrc + (size_t)8 * S_LEN, &Vs[0][w * 1024 + 512]);

    int p = 0;
    for (int ks = 0; ks < S_LEN; ks += 64, p ^= 1) {
        __syncthreads();
        if (ks + 64 < S_LEN) {
            const unsigned short* kn = ksrc + (size_t)(ks + 64) * DK_;
            const unsigned short* vn = vsrc + (ks + 64);
            GLOAD_LDS16(kn, &Ks[p ^ 1][w * 1024]);
            GLOAD_LDS16(kn + (size_t)8 * DK_, &Ks[p ^ 1][w * 1024 + 512]);
            GLOAD_LDS16(vn, &Vs[p ^ 1][w * 1024]);
            GLOAD_LDS16(vn + (size_t)8 * S_LEN, &Vs[p ^ 1][w * 1024 + 512]);
        }
        const unsigned short* KsT = &Ks[p][0];
        const unsigned short* VsT = &Vs[p][0];

#pragma unroll
        for (int kb = 0; kb < 2; kb++) {
            f32x16 st = {0.f};
#pragma unroll
            for (int s = 0; s < 4; s++) {
                bf16x8 kf = *(const bf16x8*)&KsT[(kb * 32 + ln) * 64 + ((2 * s + hf) ^ swz) * 8];
                st = __builtin_amdgcn_mfma_f32_32x32x16_bf16(kf, qf[s], st, 0, 0, 0);
            }
            float e[16];
#pragma unroll
            for (int r = 0; r < 16; r++) e[r] = EXP2F(st[r]);
            lsum += ((e[0] + e[1]) + (e[2] + e[3])) + ((e[4] + e[5]) + (e[6] + e[7]))
                  + ((e[8] + e[9]) + (e[10] + e[11])) + ((e[12] + e[13]) + (e[14] + e[15]));
            unsigned int g[8];
#pragma unroll
            for (int gi = 0; gi < 8; gi++) g[gi] = pkbf(e[2 * gi], e[2 * gi + 1]);
            pl32swap(g[0], g[2]); pl32swap(g[1], g[3]);
            pl32swap(g[4], g[6]); pl32swap(g[5], g[7]);
            bf16x8 b0, b1;
            { uint4v t = {g[0], g[1], g[2], g[3]}; __builtin_memcpy(&b0, &t, 16); }
            { uint4v t = {g[4], g[5], g[6], g[7]}; __builtin_memcpy(&b1, &t, 16); }
#pragma unroll
            for (int dt = 0; dt < 2; dt++) {
                int s0 = kb * 2;
                bf16x8 vf0 = *(const bf16x8*)&VsT[(dt * 32 + ln) * 64 + ((2 * s0 + hf) ^ swz) * 8];
                bf16x8 vf1 = *(const bf16x8*)&VsT[(dt * 32 + ln) * 64 + ((2 * s0 + 2 + hf) ^ swz) * 8];
                oacc[dt] = __builtin_amdgcn_mfma_f32_32x32x16_bf16(vf0, b0, oacc[dt], 0, 0, 0);
                oacc[dt] = __builtin_amdgcn_mfma_f32_32x32x16_bf16(vf1, b1, oacc[dt], 0, 0, 0);
            }
        }
    }

    float ltot = lsum + __shfl_xor(lsum, 32, 64);
    float inv = 1.0f / ltot;

    int bb = bh >> 3, hh = bh & 7;
    int token = bb * S_LEN + q0 + ln;
#pragma unroll
    for (int dt = 0; dt < 2; dt++)
#pragma unroll
        for (int gi = 0; gi < 8; gi++) {
            int d = dt * 32 + 2 * (gi & 1) + 8 * (gi >> 1) + 4 * hf;
            unsigned int o = pkbf(oacc[dt][2 * gi] * inv, oacc[dt][2 * gi + 1] * inv);
            *(unsigned int*)&Ao[(size_t)token * DM_ + hh * DK_ + d] = o;
        }
}

// ---------- fused split-K flash: 2 key-teams in ONE block, merge in LDS ----------
__global__ __launch_bounds__(512, 4) void flash_attn_f(const unsigned short* __restrict__ Qh,
                                                       const unsigned short* __restrict__ Kh,
                                                       const unsigned short* __restrict__ VhT,
                                                       unsigned short* __restrict__ Ao) {
    __shared__ __align__(16) unsigned char smem[65536];
    int i = blockIdx.x;
    int bh = i & 15;
    int qb = i >> 4;                               // 0..31
    int tid = threadIdx.x;
    int w = tid >> 6, lane = tid & 63;
    int team = w >> 2, wl = w & 3;
    int ln = lane & 31, hf = lane >> 5;
    int swz = ln & 7;
    int q0 = qb * 128 + wl * 32;
    int ks0 = team * (S_LEN / 2);
    int ks1 = ks0 + (S_LEN / 2);
    const unsigned short* Qp = Qh + (size_t)bh * S_LEN * DK_;
    const unsigned short* Kp = Kh + (size_t)bh * S_LEN * DK_;
    const unsigned short* Vp = VhT + (size_t)bh * DK_ * S_LEN;

    // per-team LDS: Ks[2][64*64] at team*32768, Vs[2][64*64] at +16384
    unsigned short* KsB = (unsigned short*)(smem + team * 32768);
    unsigned short* VsB = (unsigned short*)(smem + team * 32768 + 16384);

    int sr = lane >> 3;
    int sc = (lane & 7) ^ sr;
    const unsigned short* ksrc = Kp + (size_t)(wl * 16 + sr) * DK_ + sc * 8;
    const unsigned short* vsrc = Vp + (size_t)(wl * 16 + sr) * S_LEN + sc * 8;

    bf16x8 qf[4];
#pragma unroll
    for (int s = 0; s < 4; s++)
        qf[s] = *(const bf16x8*)&Qp[(size_t)(q0 + ln) * DK_ + s * 16 + hf * 8];

    f32x16 oacc[2];
    { f32x16 z = {0.f}; oacc[0] = z; oacc[1] = z; }
    float lsum = 0.f;

    GLOAD_LDS16(ksrc + (size_t)ks0 * DK_, &KsB[wl * 1024]);
    GLOAD_LDS16(ksrc + (size_t)(ks0 + 8) * DK_, &KsB[wl * 1024 + 512]);
    GLOAD_LDS16(vsrc + ks0, &VsB[wl * 1024]);
    GLOAD_LDS16(vsrc + ks0 + (size_t)8 * S_LEN, &VsB[wl * 1024 + 512]);

    int p = 0;
    for (int ks = ks0; ks < ks1; ks += 64, p ^= 1) {
        __syncthreads();   // drains DMA for buf p; all waves done reading buf p^1
        if (ks + 64 < ks1) {
            const unsigned short* kn = ksrc + (size_t)(ks + 64) * DK_;
            const unsigned short* vn = vsrc + (ks + 64);
            GLOAD_LDS16(kn, &KsB[(p ^ 1) * 4096 + wl * 1024]);
            GLOAD_LDS16(kn + (size_t)8 * DK_, &KsB[(p ^ 1) * 4096 + wl * 1024 + 512]);
            GLOAD_LDS16(vn, &VsB[(p ^ 1) * 4096 + wl * 1024]);
            GLOAD_LDS16(vn + (size_t)8 * S_LEN, &VsB[(p ^ 1) * 4096 + wl * 1024 + 512]);
        }
        const unsigned short* KsT = &KsB[p * 4096];
        const unsigned short* VsT = &VsB[p * 4096];

#pragma unroll
        for (int kb = 0; kb < 2; kb++) {
            f32x16 st = {0.f};
#pragma unroll
            for (int s = 0; s < 4; s++) {
                bf16x8 kf = *(const bf16x8*)&KsT[(kb * 32 + ln) * 64 + ((2 * s + hf) ^ swz) * 8];
                st = __builtin_amdgcn_mfma_f32_32x32x16_bf16(kf, qf[s], st, 0, 0, 0);
            }
            float e[16];
#pragma unroll
            for (int r = 0; r < 16; r++) e[r] = EXP2F(st[r]);
            lsum += ((e[0] + e[1]) + (e[2] + e[3])) + ((e[4] + e[5]) + (e[6] + e[7]))
                  + ((e[8] + e[9]) + (e[10] + e[11])) + ((e[12] + e[13]) + (e[14] + e[15]));
            unsigned int g[8];
#pragma unroll
            for (int gi = 0; gi < 8; gi++) g[gi] = pkbf(e[2 * gi], e[2 * gi + 1]);
            pl32swap(g[0], g[2]); pl32swap(g[1], g[3]);
            pl32swap(g[4], g[6]); pl32swap(g[5], g[7]);
            bf16x8 b0, b1;
            { uint4v t = {g[0], g[1], g[2], g[3]}; __builtin_memcpy(&b0, &t, 16); }
            { uint4v t = {g[4], g[5], g[6], g[7]}; __builtin_memcpy(&b1, &t, 16); }
#pragma unroll
            for (int dt = 0; dt < 2; dt++) {
                int s0 = kb * 2;
                bf16x8 vf0 = *(const bf16x8*)&VsT[(dt * 32 + ln) * 64 + ((2 * s0 + hf) ^ swz) * 8];
                bf16x8 vf1 = *(const bf16x8*)&VsT[(dt * 32 + ln) * 64 + ((2 * s0 + 2 + hf) ^ swz) * 8];
                oacc[dt] = __builtin_amdgcn_mfma_f32_32x32x16_bf16(vf0, b0, oacc[dt], 0, 0, 0);
                oacc[dt] = __builtin_amdgcn_mfma_f32_32x32x16_bf16(vf1, b1, oacc[dt], 0, 0, 0);
            }
        }
    }

    // per-team denominator (both lane-halves combined)
    float ltot = lsum + __shfl_xor(lsum, 32, 64);

    // ---- cross-team merge in LDS (K/V buffers are dead) ----
    __syncthreads();
    float* eps = (float*)smem;          // 8192 f32 = 32KB (team-0's region)
    float* epl = eps + 8192;            // 128 f32 for lsums (team-1's region)
    if (team == 1) {
#pragma unroll
        for (int dt = 0; dt < 2; dt++)
#pragma unroll
            for (int r = 0; r < 16; r++)
                eps[wl * 2048 + dt * 1024 + r * 64 + lane] = oacc[dt][r];
        if (hf == 0) epl[wl * 32 + ln] = ltot;
    }
    __syncthreads();
    if (team == 0) {
#pragma unroll
        for (int dt = 0; dt < 2; dt++)
#pragma unroll
            for (int r = 0; r < 16; r++)
                oacc[dt][r] += eps[wl * 2048 + dt * 1024 + r * 64 + lane];
        float inv = 1.0f / (ltot + epl[wl * 32 + ln]);

        int bb = bh >> 3, hh = bh & 7;
        int token = bb * S_LEN + q0 + ln;
#pragma unroll
        for (int dt = 0; dt < 2; dt++)
#pragma unroll
            for (int gi = 0; gi < 8; gi++) {
                int d = dt * 32 + 2 * (gi & 1) + 8 * (gi >> 1) + 4 * hf;
                unsigned int o = pkbf(oacc[dt][2 * gi] * inv, oacc[dt][2 * gi + 1] * inv);
                *(unsigned int*)&Ao[(size_t)token * DM_ + hh * DK_ + d] = o;
            }
    }
}

// ---------- output GEMM: out = Ao(bf16)@Wo + bo, fp32 out (LDS-DMA staged) ----------
__global__ __launch_bounds__(256, 3) void out_gemm(const unsigned short* __restrict__ A,
                                                   const unsigned short* __restrict__ Wt,
                                                   const float* __restrict__ bias, float* __restrict__ out) {
    __shared__ unsigned short As[128 * 32];
    __shared__ unsigned short Bs[128 * 32];
    int tid = threadIdx.x;
    int n0 = blockIdx.x * 128, m0 = blockIdx.y * 128;
    int w = tid >> 6, lane = tid & 63;
    int ln = lane & 15, qd = lane >> 4;
    int mb = (w >> 1) * 64, nb = (w & 1) * 64;

    int lr = lane >> 2;
    int cs = ((lane & 3) ^ (lr & 3)) * 8;
    int rdc = (qd ^ (ln & 3)) * 8;

    f32x4 acc[4][4];
#pragma unroll
    for (int i = 0; i < 4; i++)
#pragma unroll
        for (int j = 0; j < 4; j++) { f32x4 z = {0.f, 0.f, 0.f, 0.f}; acc[i][j] = z; }

    for (int kk = 0; kk < DM_; kk += 32) {
        __syncthreads();
#pragma unroll
        for (int j = 0; j < 2; j++) {
            int r0 = w * 32 + j * 16;
            GLOAD_LDS16(&A[(size_t)(m0 + r0 + lr) * DM_ + kk + cs], &As[r0 * 32]);
            GLOAD_LDS16(&Wt[(size_t)(n0 + r0 + lr) * DM_ + kk + cs], &Bs[r0 * 32]);
        }
        __syncthreads();
        bf16x8 af[4], bf[4];
#pragma unroll
        for (int mt = 0; mt < 4; mt++) af[mt] = *(const bf16x8*)&As[(mb + mt * 16 + ln) * 32 + rdc];
#pragma unroll
        for (int nt = 0; nt < 4; nt++) bf[nt] = *(const bf16x8*)&Bs[(nb + nt * 16 + ln) * 32 + rdc];
#pragma unroll
        for (int mt = 0; mt < 4; mt++)
#pragma unroll
            for (int nt = 0; nt < 4; nt++)
                acc[mt][nt] = __builtin_amdgcn_mfma_f32_16x16x32_bf16(af[mt], bf[nt], acc[mt][nt], 0, 0, 0);
    }

    float bv[4];
#pragma unroll
    for (int nt = 0; nt < 4; nt++) bv[nt] = bias[n0 + nb + nt * 16 + ln];
#pragma unroll
    for (int mt = 0; mt < 4; mt++) {
        int mrow0 = m0 + mb + mt * 16 + qd * 4;
#pragma unroll
        for (int nt = 0; nt < 4; nt++) {
            int ncol = n0 + nb + nt * 16 + ln;
#pragma unroll
            for (int r = 0; r < 4; r++)
                out[(size_t)(mrow0 + r) * DM_ + ncol] = acc[mt][nt][r] + bv[nt];
        }
    }
}

extern "C" void kernel_launch(void* const* d_in, const int* in_sizes, int n_in,
                              void* d_out, int out_size, void* d_ws, size_t ws_size,
                              hipStream_t stream) {
    const float* q  = (const float*)d_in[0];
    const float* k  = (const float*)d_in[1];
    const float* v  = (const float*)d_in[2];
    const float* Wq = (const float*)d_in[3];
    const float* bq = (const float*)d_in[4];
    const float* Wk = (const float*)d_in[5];
    const float* bk = (const float*)d_in[6];
    const float* Wv = (const float*)d_in[7];
    const float* bv = (const float*)d_in[8];
    const float* Wo = (const float*)d_in[9];
    const float* bo = (const float*)d_in[10];
    float* out = (float*)d_out;

    unsigned short* Wt  = (unsigned short*)d_ws;
    unsigned short* Qh  = Wt + (size_t)4 * DM_ * DM_;
    unsigned short* Kh  = Qh + (size_t)NTOK * DM_;
    unsigned short* VhT = Kh + (size_t)NTOK * DM_;
    unsigned short* tail = VhT + (size_t)NTOK * DM_;

    size_t need_bf = ((size_t)4 * DM_ * DM_ + (size_t)6 * NTOK * DM_) * 2;

    if (ws_size >= need_bf) {
        unsigned short* Xbf = tail;   // Ao aliases Xbf head (Xbf dead before flash writes Ao)
        unsigned short* Ao = tail;
        prep<<<dim3(2304), 256, 0, stream>>>(q, k, v, Wq, Wk, Wv, Wo, Xbf, Wt);
        qkv_bf<<<dim3(4, 64, 3), 256, 0, stream>>>(Xbf, Wt, bq, bk, bv, Qh, Kh, VhT);
        flash_attn_f<<<dim3(512), 512, 0, stream>>>(Qh, Kh, VhT, Ao);
        out_gemm<<<dim3(4, 64), 256, 0, stream>>>(Ao, Wt + (size_t)3 * DM_ * DM_, bo, out);
    } else {
        unsigned short* Ao = tail;
        wtrans<<<dim3(8, 8, 4), 256, 0, stream>>>(Wq, Wk, Wv, Wo, Wt);
        qkv_proj<<<dim3(4, 64, 3), 256, 0, stream>>>(q, k, v, Wt, bq, bk, bv, Qh, Kh, VhT);
        flash_attn<<<dim3(512), 256, 0, stream>>>(Qh, Kh, VhT, Ao);
        out_gemm<<<dim3(4, 64), 256, 0, stream>>>(Ao, Wt + (size_t)3 * DM_ * DM_, bo, out);
    }
}

// Round 10
// 234.847 us; speedup vs baseline: 1.1826x; 1.0191x over previous
//
#include <hip/hip_runtime.h>
#include <hip/hip_bf16.h>

#define NHEAD 8
#define DK_ 64
#define DM_ 512
#define S_LEN 4096
#define NTOK 8192

typedef __bf16 bf16x8 __attribute__((ext_vector_type(8)));
typedef float f32x4 __attribute__((ext_vector_type(4)));
typedef float f32x16 __attribute__((ext_vector_type(16)));
typedef unsigned int uint4v __attribute__((ext_vector_type(4)));

__device__ __forceinline__ unsigned short f2bf(float f) {
    union { float f; unsigned u; } x; x.f = f;
    unsigned u = x.u;
    u += 0x7FFFu + ((u >> 16) & 1u);   // round-to-nearest-even (inputs finite)
    return (unsigned short)(u >> 16);
}

// packed f32x2 -> bf16x2 (gfx950 HW op when available; RNE either way)
#if __has_builtin(__builtin_amdgcn_cvt_pk_bf16_f32)
__device__ __forceinline__ unsigned int pkbf(float a, float b) {
    auto r = __builtin_amdgcn_cvt_pk_bf16_f32(a, b);
    unsigned int u; __builtin_memcpy(&u, &r, 4); return u;
}
#else
__device__ __forceinline__ unsigned int pkbf(float a, float b) {
    return (unsigned)f2bf(a) | ((unsigned)f2bf(b) << 16);
}
#endif

#if __has_builtin(__builtin_amdgcn_exp2f)
#define EXP2F(x) __builtin_amdgcn_exp2f(x)
#else
#define EXP2F(x) exp2f(x)
#endif

// lane-half <-> reg exchange: new_a = {a_lo, b_lo}, new_b = {a_hi, b_hi}
#if __has_builtin(__builtin_amdgcn_permlane32_swap)
__device__ __forceinline__ void pl32swap(unsigned int& a, unsigned int& b) {
    auto r = __builtin_amdgcn_permlane32_swap(a, b, false, false);
    a = r[0]; b = r[1];
}
#else
__device__ __forceinline__ void pl32swap(unsigned int& a, unsigned int& b) {
    int lane = threadIdx.x & 63;
    unsigned int ax = __shfl_xor((int)a, 32, 64);
    unsigned int bx = __shfl_xor((int)b, 32, 64);
    unsigned int na = (lane < 32) ? a : bx;
    unsigned int nb = (lane < 32) ? ax : b;
    a = na; b = nb;
}
#endif

// async global->LDS, 16B per lane; LDS dest = wave-uniform base + lane*16
#define GLOAD_LDS16(gptr, ldsbase) \
    __builtin_amdgcn_global_load_lds((const __attribute__((address_space(1))) unsigned int*)(gptr), \
                                     (__attribute__((address_space(3))) unsigned int*)(ldsbase), 16, 0, 0)

// ---------- prep v2: grid-stride xcvt (blocks 0..2047) + wtrans (2048..2303) ----------
__global__ __launch_bounds__(256) void prep(const float* __restrict__ q, const float* __restrict__ k,
                                            const float* __restrict__ v,
                                            const float* __restrict__ Wq, const float* __restrict__ Wk,
                                            const float* __restrict__ Wv, const float* __restrict__ Wo,
                                            unsigned short* __restrict__ Xbf, unsigned short* __restrict__ Wt) {
    __shared__ float t[64][65];
    int bi = blockIdx.x;
    int tid = threadIdx.x;
    if (bi < 2048) {
        size_t gtid = (size_t)bi * 256 + tid;
#pragma unroll
        for (int it = 0; it < 6; it++) {
            size_t c = gtid + (size_t)it * 524288;   // chunk idx in [0, 3*NTOK*DM_/4)
            size_t e = c * 4;                        // element idx; NTOK*DM_ = 2^22
            int z = (int)(e >> 22);
            size_t off = e & 4194303u;
            const float* X = (z == 0) ? q : (z == 1) ? k : v;
            float4 val = *(const float4*)&X[off];
            uint2 o; o.x = pkbf(val.x, val.y); o.y = pkbf(val.z, val.w);
            *(uint2*)&Xbf[e] = o;
        }
        return;
    }
    int wi = bi - 2048;                              // 0..255
    int zz = wi >> 6;
    int bn = (wi & 7) * 64, bk = ((wi >> 3) & 7) * 64;
    const float* W = (zz == 0) ? Wq : (zz == 1) ? Wk : (zz == 2) ? Wv : Wo;
    unsigned short* out = Wt + (size_t)zz * DM_ * DM_;
    int r0 = tid >> 4, c4 = (tid & 15) * 4;
#pragma unroll
    for (int i = 0; i < 4; i++) {
        int r = r0 + i * 16;
        float4 vv = *(const float4*)&W[(size_t)(bk + r) * DM_ + bn + c4];
        t[r][c4] = vv.x; t[r][c4 + 1] = vv.y; t[r][c4 + 2] = vv.z; t[r][c4 + 3] = vv.w;
    }
    __syncthreads();
    int n0 = tid >> 4, k4 = (tid & 15) * 4;
#pragma unroll
    for (int i = 0; i < 4; i++) {
        int n = n0 + i * 16;
        ushort4 o;
        o.x = f2bf(t[k4 + 0][n]); o.y = f2bf(t[k4 + 1][n]);
        o.z = f2bf(t[k4 + 2][n]); o.w = f2bf(t[k4 + 3][n]);
        *(ushort4*)&out[(size_t)(bn + n) * DM_ + bk + k4] = o;
    }
}

// ---------- standalone wtrans (smallest-ws fallback path) ----------
__global__ __launch_bounds__(256) void wtrans(const float* __restrict__ Wq, const float* __restrict__ Wk,
                                              const float* __restrict__ Wv, const float* __restrict__ Wo,
                                              unsigned short* __restrict__ Wt) {
    int z = blockIdx.z;
    const float* W = (z == 0) ? Wq : (z == 1) ? Wk : (z == 2) ? Wv : Wo;
    unsigned short* out = Wt + (size_t)z * DM_ * DM_;
    __shared__ float t[64][65];
    int bn = blockIdx.x * 64, bk = blockIdx.y * 64;
    int tid = threadIdx.x;
    int r0 = tid >> 4, c4 = (tid & 15) * 4;
#pragma unroll
    for (int i = 0; i < 4; i++) {
        int r = r0 + i * 16;
        float4 v = *(const float4*)&W[(size_t)(bk + r) * DM_ + bn + c4];
        t[r][c4] = v.x; t[r][c4 + 1] = v.y; t[r][c4 + 2] = v.z; t[r][c4 + 3] = v.w;
    }
    __syncthreads();
    int n0 = tid >> 4, k4 = (tid & 15) * 4;
#pragma unroll
    for (int i = 0; i < 4; i++) {
        int n = n0 + i * 16;
        ushort4 o;
        o.x = f2bf(t[k4 + 0][n]); o.y = f2bf(t[k4 + 1][n]);
        o.z = f2bf(t[k4 + 2][n]); o.w = f2bf(t[k4 + 3][n]);
        *(ushort4*)&out[(size_t)(bn + n) * DM_ + bk + k4] = o;
    }
}

// shared epilogue for projection GEMMs
__device__ __forceinline__ void proj_epilogue(int z, f32x4 (&acc)[4][4], const float* bias,
                                              unsigned short* out, float scale,
                                              int m0, int n0, int mb, int nb, int ln, int qd) {
    float bvv[4];
#pragma unroll
    for (int nt = 0; nt < 4; nt++) bvv[nt] = bias[n0 + nb + nt * 16 + ln];
#pragma unroll
    for (int mt = 0; mt < 4; mt++) {
        int mrow0 = m0 + mb + mt * 16 + qd * 4;
        int b = mrow0 >> 12, s = mrow0 & 4095;
#pragma unroll
        for (int nt = 0; nt < 4; nt++) {
            int ncol = n0 + nb + nt * 16 + ln;
            int h = ncol >> 6, d = ncol & 63;
            if (z == 2) {
                uint2 o;
                o.x = pkbf((acc[mt][nt][0] + bvv[nt]) * scale, (acc[mt][nt][1] + bvv[nt]) * scale);
                o.y = pkbf((acc[mt][nt][2] + bvv[nt]) * scale, (acc[mt][nt][3] + bvv[nt]) * scale);
                *(uint2*)&out[((size_t)(b * NHEAD + h) * DK_ + d) * S_LEN + s] = o;
            } else {
#pragma unroll
                for (int r = 0; r < 4; r++)
                    out[((size_t)(b * NHEAD + h) * S_LEN + (s + r)) * DK_ + d] =
                        f2bf((acc[mt][nt][r] + bvv[nt]) * scale);
            }
        }
    }
}

// ---------- fused QKV projection, LDS-DMA staged, BK=64 ----------
// r9: rest-of-pipeline pinned at 134us across all launch configs -> test the
// barrier-stall hypothesis: BK 32->64 halves barrier count (16->8) at same
// DMA volume. LDS [128][64] = 16KB/side (32KB, 3 blocks/CU). Swizzle
// re-derived for 8-chunk rows: src chunk = (lane&7)^(row&7) (involution),
// read chunk = (ks2*4+qd)^(ln&7) -> even 8-lane-per-bank-group.
__global__ __launch_bounds__(256, 3) void qkv_bf(const unsigned short* __restrict__ Xbf,
                                                 const unsigned short* __restrict__ Wt,
                                                 const float* __restrict__ bq, const float* __restrict__ bk,
                                                 const float* __restrict__ bv,
                                                 unsigned short* __restrict__ Qh, unsigned short* __restrict__ Kh,
                                                 unsigned short* __restrict__ VhT) {
    int z = blockIdx.z;
    const unsigned short* X = Xbf + (size_t)z * NTOK * DM_;
    const unsigned short* W = Wt + (size_t)z * DM_ * DM_;
    const float* bias = (z == 0) ? bq : (z == 1) ? bk : bv;
    unsigned short* out = (z == 0) ? Qh : (z == 1) ? Kh : VhT;
    float scale = (z == 0) ? 0.125f * 1.44269504f : 1.0f;

    __shared__ unsigned short As[128 * 64];
    __shared__ unsigned short Bs[128 * 64];
    int tid = threadIdx.x;
    int n0 = blockIdx.x * 128, m0 = blockIdx.y * 128;
    int w = tid >> 6, lane = tid & 63;
    int ln = lane & 15, qd = lane >> 4;
    int mb = (w >> 1) * 64, nb = (w & 1) * 64;

    int lr8 = lane >> 3;                             // local row 0..7 per 8-row slab
    int cs = ((lane & 7) ^ lr8) * 8;                 // pre-swizzled source chunk (elems)

    f32x4 acc[4][4];
#pragma unroll
    for (int i = 0; i < 4; i++)
#pragma unroll
        for (int j = 0; j < 4; j++) { f32x4 zz = {0.f, 0.f, 0.f, 0.f}; acc[i][j] = zz; }

    for (int kk = 0; kk < DM_; kk += 64) {
        __syncthreads();
#pragma unroll
        for (int j = 0; j < 4; j++) {
            int r0 = w * 32 + j * 8;
            GLOAD_LDS16(&X[(size_t)(m0 + r0 + lr8) * DM_ + kk + cs], &As[r0 * 64]);
            GLOAD_LDS16(&W[(size_t)(n0 + r0 + lr8) * DM_ + kk + cs], &Bs[r0 * 64]);
        }
        __syncthreads();
#pragma unroll
        for (int ks2 = 0; ks2 < 2; ks2++) {
            int rc = ((ks2 * 4 + qd) ^ (ln & 7)) * 8;
            bf16x8 af[4], bf[4];
#pragma unroll
            for (int mt = 0; mt < 4; mt++) af[mt] = *(const bf16x8*)&As[(mb + mt * 16 + ln) * 64 + rc];
#pragma unroll
            for (int nt = 0; nt < 4; nt++) bf[nt] = *(const bf16x8*)&Bs[(nb + nt * 16 + ln) * 64 + rc];
#pragma unroll
            for (int mt = 0; mt < 4; mt++)
#pragma unroll
                for (int nt = 0; nt < 4; nt++)
                    acc[mt][nt] = __builtin_amdgcn_mfma_f32_16x16x32_bf16(af[mt], bf[nt], acc[mt][nt], 0, 0, 0);
        }
    }
    proj_epilogue(z, acc, bias, out, scale, m0, n0, mb, nb, ln, qd);
}

// ---------- fallback fused QKV projection from fp32 X (small ws) ----------
__global__ __launch_bounds__(256, 3) void qkv_proj(const float* __restrict__ xq, const float* __restrict__ xk,
                                                   const float* __restrict__ xv, const unsigned short* __restrict__ Wt,
                                                   const float* __restrict__ bq, const float* __restrict__ bk,
                                                   const float* __restrict__ bv,
                                                   unsigned short* __restrict__ Qh, unsigned short* __restrict__ Kh,
                                                   unsigned short* __restrict__ VhT) {
    int z = blockIdx.z;
    const float* X = (z == 0) ? xq : (z == 1) ? xk : xv;
    const unsigned short* W = Wt + (size_t)z * DM_ * DM_;
    const float* bias = (z == 0) ? bq : (z == 1) ? bk : bv;
    unsigned short* out = (z == 0) ? Qh : (z == 1) ? Kh : VhT;
    float scale = (z == 0) ? 0.125f * 1.44269504f : 1.0f;

    __shared__ unsigned short As[128 * 40];
    __shared__ unsigned short Bs[128 * 40];
    int tid = threadIdx.x;
    int n0 = blockIdx.x * 128, m0 = blockIdx.y * 128;
    int w = tid >> 6, lane = tid & 63;
    int ln = lane & 15, qd = lane >> 4;
    int mb = (w >> 1) * 64, nb = (w & 1) * 64;

    f32x4 acc[4][4];
#pragma unroll
    for (int i = 0; i < 4; i++)
#pragma unroll
        for (int j = 0; j < 4; j++) { f32x4 zz = {0.f, 0.f, 0.f, 0.f}; acc[i][j] = zz; }

    for (int kk = 0; kk < DM_; kk += 32) {
        __syncthreads();
#pragma unroll
        for (int i = 0; i < 4; i++) {
            int idx = i * 256 + tid;
            int row = idx >> 3, k4 = (idx & 7) * 4;
            float4 v = *(const float4*)&X[(size_t)(m0 + row) * DM_ + kk + k4];
            uint2 o; o.x = pkbf(v.x, v.y); o.y = pkbf(v.z, v.w);
            *(uint2*)&As[row * 40 + k4] = o;
        }
#pragma unroll
        for (int i = 0; i < 2; i++) {
            int idx = i * 256 + tid;
            int row = idx >> 2, k8 = (idx & 3) * 8;
            uint4 v = *(const uint4*)&W[(size_t)(n0 + row) * DM_ + kk + k8];
            *(uint4*)&Bs[row * 40 + k8] = v;
        }
        __syncthreads();
        bf16x8 af[4], bf[4];
#pragma unroll
        for (int mt = 0; mt < 4; mt++) af[mt] = *(const bf16x8*)&As[(mb + mt * 16 + ln) * 40 + qd * 8];
#pragma unroll
        for (int nt = 0; nt < 4; nt++) bf[nt] = *(const bf16x8*)&Bs[(nb + nt * 16 + ln) * 40 + qd * 8];
#pragma unroll
        for (int mt = 0; mt < 4; mt++)
#pragma unroll
            for (int nt = 0; nt < 4; nt++)
                acc[mt][nt] = __builtin_amdgcn_mfma_f32_16x16x32_bf16(af[mt], bf[nt], acc[mt][nt], 0, 0, 0);
    }
    proj_epilogue(z, acc, bias, out, scale, m0, n0, mb, nb, ln, qd);
}

// ---------- flash attention (legacy single-pass, small-ws fallback) ----------
__global__ __launch_bounds__(256, 2) void flash_attn(const unsigned short* __restrict__ Qh,
                                                     const unsigned short* __restrict__ Kh,
                                                     const unsigned short* __restrict__ VhT,
                                                     unsigned short* __restrict__ Ao) {
    __shared__ unsigned short Ks[2][64 * 64];     // 16 KB
    __shared__ unsigned short Vs[2][64 * 64];     // 16 KB
    int i = blockIdx.x;
    int bh = (i & 7) + 8 * ((i >> 3) & 1);
    int qb = i >> 4;
    int tid = threadIdx.x;
    int w = tid >> 6, lane = tid & 63;
    int ln = lane & 31, hf = lane >> 5;
    int swz = ln & 7;
    int q0 = qb * 128 + w * 32;
    const unsigned short* Qp = Qh + (size_t)bh * S_LEN * DK_;
    const unsigned short* Kp = Kh + (size_t)bh * S_LEN * DK_;
    const unsigned short* Vp = VhT + (size_t)bh * DK_ * S_LEN;

    int sr = lane >> 3;
    int sc = (lane & 7) ^ sr;
    const unsigned short* ksrc = Kp + (size_t)(w * 16 + sr) * DK_ + sc * 8;
    const unsigned short* vsrc = Vp + (size_t)(w * 16 + sr) * S_LEN + sc * 8;

    bf16x8 qf[4];
#pragma unroll
    for (int s = 0; s < 4; s++)
        qf[s] = *(const bf16x8*)&Qp[(size_t)(q0 + ln) * DK_ + s * 16 + hf * 8];

    f32x16 oacc[2];
    { f32x16 z = {0.f}; oacc[0] = z; oacc[1] = z; }
    float lsum = 0.f;

    GLOAD_LDS16(ksrc, &Ks[0][w * 1024]);
    GLOAD_LDS16(ksrc + (size_t)8 * DK_, &Ks[0][w * 1024 + 512]);
    GLOAD_LDS16(vsrc, &Vs[0][w * 1024]);
    GLOAD_LDS16(vsrc + (size_t)8 * S_LEN, &Vs[0][w * 1024 + 512]);

    int p = 0;
    for (int ks = 0; ks < S_LEN; ks += 64, p ^= 1) {
        __syncthreads();
        if (ks + 64 < S_LEN) {
            const unsigned short* kn = ksrc + (size_t)(ks + 64) * DK_;
            const unsigned short* vn = vsrc + (ks + 64);
            GLOAD_LDS16(kn, &Ks[p ^ 1][w * 1024]);
            GLOAD_LDS16(kn + (size_t)8 * DK_, &Ks[p ^ 1][w * 1024 + 512]);
            GLOAD_LDS16(vn, &Vs[p ^ 1][w * 1024]);
            GLOAD_LDS16(vn + (size_t)8 * S_LEN, &Vs[p ^ 1][w * 1024 + 512]);
        }
        const unsigned short* KsT = &Ks[p][0];
        const unsigned short* VsT = &Vs[p][0];

#pragma unroll
        for (int kb = 0; kb < 2; kb++) {
            f32x16 st = {0.f};
#pragma unroll
            for (int s = 0; s < 4; s++) {
                bf16x8 kf = *(const bf16x8*)&KsT[(kb * 32 + ln) * 64 + ((2 * s + hf) ^ swz) * 8];
                st = __builtin_amdgcn_mfma_f32_32x32x16_bf16(kf, qf[s], st, 0, 0, 0);
            }
            float e[16];
#pragma unroll
            for (int r = 0; r < 16; r++) e[r] = EXP2F(st[r]);
            lsum += ((e[0] + e[1]) + (e[2] + e[3])) + ((e[4] + e[5]) + (e[6] + e[7]))
                  + ((e[8] + e[9]) + (e[10] + e[11])) + ((e[12] + e[13]) + (e[14] + e[15]));
            unsigned int g[8];
#pragma unroll
            for (int gi = 0; gi < 8; gi++) g[gi] = pkbf(e[2 * gi], e[2 * gi + 1]);
            pl32swap(g[0], g[2]); pl32swap(g[1], g[3]);
            pl32swap(g[4], g[6]); pl32swap(g[5], g[7]);
            bf16x8 b0, b1;
            { uint4v t = {g[0], g[1], g[2], g[3]}; __builtin_memcpy(&b0, &t, 16); }
            { uint4v t = {g[4], g[5], g[6], g[7]}; __builtin_memcpy(&b1, &t, 16); }
#pragma unroll
            for (int dt = 0; dt < 2; dt++) {
                int s0 = kb * 2;
                bf16x8 vf0 = *(const bf16x8*)&VsT[(dt * 32 + ln) * 64 + ((2 * s0 + hf) ^ swz) * 8];
                bf16x8 vf1 = *(const bf16x8*)&VsT[(dt * 32 + ln) * 64 + ((2 * s0 + 2 + hf) ^ swz) * 8];
                oacc[dt] = __builtin_amdgcn_mfma_f32_32x32x16_bf16(vf0, b0, oacc[dt], 0, 0, 0);
                oacc[dt] = __builtin_amdgcn_mfma_f32_32x32x16_bf16(vf1, b1, oacc[dt], 0, 0, 0);
            }
        }
    }

    float ltot = lsum + __shfl_xor(lsum, 32, 64);
    float inv = 1.0f / ltot;

    int bb = bh >> 3, hh = bh & 7;
    int token = bb * S_LEN + q0 + ln;
#pragma unroll
    for (int dt = 0; dt < 2; dt++)
#pragma unroll
        for (int gi = 0; gi < 8; gi++) {
            int d = dt * 32 + 2 * (gi & 1) + 8 * (gi >> 1) + 4 * hf;
            unsigned int o = pkbf(oacc[dt][2 * gi] * inv, oacc[dt][2 * gi + 1] * inv);
            *(unsigned int*)&Ao[(size_t)token * DM_ + hh * DK_ + d] = o;
        }
}

// ---------- fused split-K flash + ones-MFMA denominator ----------
// r9 pipe model: VALUBusy 55% = 2x MfmaUtil 28% -> VALU-issue-heavy. The
// 15-add lsum tree + final shfl per kb-block is replaced by 2 MFMAs with a
// ones A-operand on the ALREADY-BUILT bf16 P fragments: every C-row of
// mfma(1s,P) = sum_k P[k][q]; accumulated into lacc, lacc[0] = full team
// denominator (no shfl). Also makes numerator/denominator use identical
// bf16 weights (consistent convex combination).
__global__ __launch_bounds__(512, 4) void flash_attn_f(const unsigned short* __restrict__ Qh,
                                                       const unsigned short* __restrict__ Kh,
                                                       const unsigned short* __restrict__ VhT,
                                                       unsigned short* __restrict__ Ao) {
    __shared__ __align__(16) unsigned char smem[65536];
    int i = blockIdx.x;
    int bh = i & 15;
    int qb = i >> 4;                               // 0..31
    int tid = threadIdx.x;
    int w = tid >> 6, lane = tid & 63;
    int team = w >> 2, wl = w & 3;
    int ln = lane & 31, hf = lane >> 5;
    int swz = ln & 7;
    int q0 = qb * 128 + wl * 32;
    int ks0 = team * (S_LEN / 2);
    int ks1 = ks0 + (S_LEN / 2);
    const unsigned short* Qp = Qh + (size_t)bh * S_LEN * DK_;
    const unsigned short* Kp = Kh + (size_t)bh * S_LEN * DK_;
    const unsigned short* Vp = VhT + (size_t)bh * DK_ * S_LEN;

    // per-team LDS: Ks[2][64*64] at team*32768, Vs[2][64*64] at +16384
    unsigned short* KsB = (unsigned short*)(smem + team * 32768);
    unsigned short* VsB = (unsigned short*)(smem + team * 32768 + 16384);

    int sr = lane >> 3;
    int sc = (lane & 7) ^ sr;
    const unsigned short* ksrc = Kp + (size_t)(wl * 16 + sr) * DK_ + sc * 8;
    const unsigned short* vsrc = Vp + (size_t)(wl * 16 + sr) * S_LEN + sc * 8;

    bf16x8 qf[4];
#pragma unroll
    for (int s = 0; s < 4; s++)
        qf[s] = *(const bf16x8*)&Qp[(size_t)(q0 + ln) * DK_ + s * 16 + hf * 8];

    bf16x8 ones;
#pragma unroll
    for (int t = 0; t < 8; t++) ones[t] = (__bf16)1.0f;

    f32x16 oacc[2], lacc;
    { f32x16 z = {0.f}; oacc[0] = z; oacc[1] = z; lacc = z; }

    GLOAD_LDS16(ksrc + (size_t)ks0 * DK_, &KsB[wl * 1024]);
    GLOAD_LDS16(ksrc + (size_t)(ks0 + 8) * DK_, &KsB[wl * 1024 + 512]);
    GLOAD_LDS16(vsrc + ks0, &VsB[wl * 1024]);
    GLOAD_LDS16(vsrc + ks0 + (size_t)8 * S_LEN, &VsB[wl * 1024 + 512]);

    int p = 0;
    for (int ks = ks0; ks < ks1; ks += 64, p ^= 1) {
        __syncthreads();   // drains DMA for buf p; all waves done reading buf p^1
        if (ks + 64 < ks1) {
            const unsigned short* kn = ksrc + (size_t)(ks + 64) * DK_;
            const unsigned short* vn = vsrc + (ks + 64);
            GLOAD_LDS16(kn, &KsB[(p ^ 1) * 4096 + wl * 1024]);
            GLOAD_LDS16(kn + (size_t)8 * DK_, &KsB[(p ^ 1) * 4096 + wl * 1024 + 512]);
            GLOAD_LDS16(vn, &VsB[(p ^ 1) * 4096 + wl * 1024]);
            GLOAD_LDS16(vn + (size_t)8 * S_LEN, &VsB[(p ^ 1) * 4096 + wl * 1024 + 512]);
        }
        const unsigned short* KsT = &KsB[p * 4096];
        const unsigned short* VsT = &VsB[p * 4096];

#pragma unroll
        for (int kb = 0; kb < 2; kb++) {
            f32x16 st = {0.f};
#pragma unroll
            for (int s = 0; s < 4; s++) {
                bf16x8 kf = *(const bf16x8*)&KsT[(kb * 32 + ln) * 64 + ((2 * s + hf) ^ swz) * 8];
                st = __builtin_amdgcn_mfma_f32_32x32x16_bf16(kf, qf[s], st, 0, 0, 0);
            }
            float e[16];
#pragma unroll
            for (int r = 0; r < 16; r++) e[r] = EXP2F(st[r]);
            unsigned int g[8];
#pragma unroll
            for (int gi = 0; gi < 8; gi++) g[gi] = pkbf(e[2 * gi], e[2 * gi + 1]);
            pl32swap(g[0], g[2]); pl32swap(g[1], g[3]);
            pl32swap(g[4], g[6]); pl32swap(g[5], g[7]);
            bf16x8 b0, b1;
            { uint4v t = {g[0], g[1], g[2], g[3]}; __builtin_memcpy(&b0, &t, 16); }
            { uint4v t = {g[4], g[5], g[6], g[7]}; __builtin_memcpy(&b1, &t, 16); }
#pragma unroll
            for (int dt = 0; dt < 2; dt++) {
                int s0 = kb * 2;
                bf16x8 vf0 = *(const bf16x8*)&VsT[(dt * 32 + ln) * 64 + ((2 * s0 + hf) ^ swz) * 8];
                bf16x8 vf1 = *(const bf16x8*)&VsT[(dt * 32 + ln) * 64 + ((2 * s0 + 2 + hf) ^ swz) * 8];
                oacc[dt] = __builtin_amdgcn_mfma_f32_32x32x16_bf16(vf0, b0, oacc[dt], 0, 0, 0);
                oacc[dt] = __builtin_amdgcn_mfma_f32_32x32x16_bf16(vf1, b1, oacc[dt], 0, 0, 0);
            }
            // denominator via matrix pipe: every row of mfma(1s,P) = sum_k P[k][q]
            lacc = __builtin_amdgcn_mfma_f32_32x32x16_bf16(ones, b0, lacc, 0, 0, 0);
            lacc = __builtin_amdgcn_mfma_f32_32x32x16_bf16(ones, b1, lacc, 0, 0, 0);
        }
    }

    // per-team denominator: lacc rows all equal the per-q sum (A = ones)
    float ltot = lacc[0];

    // ---- cross-team merge in LDS (K/V buffers are dead) ----
    __syncthreads();
    float* eps = (float*)smem;          // 8192 f32 = 32KB (team-0's region)
    float* epl = eps + 8192;            // 128 f32 for lsums (team-1's region)
    if (team == 1) {
#pragma unroll
        for (int dt = 0; dt < 2; dt++)
#pragma unroll
            for (int r = 0; r < 16; r++)
                eps[wl * 2048 + dt * 1024 + r * 64 + lane] = oacc[dt][r];
        if (hf == 0) epl[wl * 32 + ln] = ltot;
    }
    __syncthreads();
    if (team == 0) {
#pragma unroll
        for (int dt = 0; dt < 2; dt++)
#pragma unroll
            for (int r = 0; r < 16; r++)
                oacc[dt][r] += eps[wl * 2048 + dt * 1024 + r * 64 + lane];
        float inv = 1.0f / (ltot + epl[wl * 32 + ln]);

        int bb = bh >> 3, hh = bh & 7;
        int token = bb * S_LEN + q0 + ln;
#pragma unroll
        for (int dt = 0; dt < 2; dt++)
#pragma unroll
            for (int gi = 0; gi < 8; gi++) {
                int d = dt * 32 + 2 * (gi & 1) + 8 * (gi >> 1) + 4 * hf;
                unsigned int o = pkbf(oacc[dt][2 * gi] * inv, oacc[dt][2 * gi + 1] * inv);
                *(unsigned int*)&Ao[(size_t)token * DM_ + hh * DK_ + d] = o;
            }
    }
}

// ---------- output GEMM: out = Ao(bf16)@Wo + bo, fp32 out (LDS-DMA, BK=64) ----------
__global__ __launch_bounds__(256, 3) void out_gemm(const unsigned short* __restrict__ A,
                                                   const unsigned short* __restrict__ Wt,
                                                   const float* __restrict__ bias, float* __restrict__ out) {
    __shared__ unsigned short As[128 * 64];
    __shared__ unsigned short Bs[128 * 64];
    int tid = threadIdx.x;
    int n0 = blockIdx.x * 128, m0 = blockIdx.y * 128;
    int w = tid >> 6, lane = tid & 63;
    int ln = lane & 15, qd = lane >> 4;
    int mb = (w >> 1) * 64, nb = (w & 1) * 64;

    int lr8 = lane >> 3;
    int cs = ((lane & 7) ^ lr8) * 8;

    f32x4 acc[4][4];
#pragma unroll
    for (int i = 0; i < 4; i++)
#pragma unroll
        for (int j = 0; j < 4; j++) { f32x4 z = {0.f, 0.f, 0.f, 0.f}; acc[i][j] = z; }

    for (int kk = 0; kk < DM_; kk += 64) {
        __syncthreads();
#pragma unroll
        for (int j = 0; j < 4; j++) {
            int r0 = w * 32 + j * 8;
            GLOAD_LDS16(&A[(size_t)(m0 + r0 + lr8) * DM_ + kk + cs], &As[r0 * 64]);
            GLOAD_LDS16(&Wt[(size_t)(n0 + r0 + lr8) * DM_ + kk + cs], &Bs[r0 * 64]);
        }
        __syncthreads();
#pragma unroll
        for (int ks2 = 0; ks2 < 2; ks2++) {
            int rc = ((ks2 * 4 + qd) ^ (ln & 7)) * 8;
            bf16x8 af[4], bf[4];
#pragma unroll
            for (int mt = 0; mt < 4; mt++) af[mt] = *(const bf16x8*)&As[(mb + mt * 16 + ln) * 64 + rc];
#pragma unroll
            for (int nt = 0; nt < 4; nt++) bf[nt] = *(const bf16x8*)&Bs[(nb + nt * 16 + ln) * 64 + rc];
#pragma unroll
            for (int mt = 0; mt < 4; mt++)
#pragma unroll
                for (int nt = 0; nt < 4; nt++)
                    acc[mt][nt] = __builtin_amdgcn_mfma_f32_16x16x32_bf16(af[mt], bf[nt], acc[mt][nt], 0, 0, 0);
        }
    }

    float bv[4];
#pragma unroll
    for (int nt = 0; nt < 4; nt++) bv[nt] = bias[n0 + nb + nt * 16 + ln];
#pragma unroll
    for (int mt = 0; mt < 4; mt++) {
        int mrow0 = m0 + mb + mt * 16 + qd * 4;
#pragma unroll
        for (int nt = 0; nt < 4; nt++) {
            int ncol = n0 + nb + nt * 16 + ln;
#pragma unroll
            for (int r = 0; r < 4; r++)
                out[(size_t)(mrow0 + r) * DM_ + ncol] = acc[mt][nt][r] + bv[nt];
        }
    }
}

extern "C" void kernel_launch(void* const* d_in, const int* in_sizes, int n_in,
                              void* d_out, int out_size, void* d_ws, size_t ws_size,
                              hipStream_t stream) {
    const float* q  = (const float*)d_in[0];
    const float* k  = (const float*)d_in[1];
    const float* v  = (const float*)d_in[2];
    const float* Wq = (const float*)d_in[3];
    const float* bq = (const float*)d_in[4];
    const float* Wk = (const float*)d_in[5];
    const float* bk = (const float*)d_in[6];
    const float* Wv = (const float*)d_in[7];
    const float* bv = (const float*)d_in[8];
    const float* Wo = (const float*)d_in[9];
    const float* bo = (const float*)d_in[10];
    float* out = (float*)d_out;

    unsigned short* Wt  = (unsigned short*)d_ws;
    unsigned short* Qh  = Wt + (size_t)4 * DM_ * DM_;
    unsigned short* Kh  = Qh + (size_t)NTOK * DM_;
    unsigned short* VhT = Kh + (size_t)NTOK * DM_;
    unsigned short* tail = VhT + (size_t)NTOK * DM_;

    size_t need_bf = ((size_t)4 * DM_ * DM_ + (size_t)6 * NTOK * DM_) * 2;

    if (ws_size >= need_bf) {
        unsigned short* Xbf = tail;   // Ao aliases Xbf head (Xbf dead before flash writes Ao)
        unsigned short* Ao = tail;
        prep<<<dim3(2304), 256, 0, stream>>>(q, k, v, Wq, Wk, Wv, Wo, Xbf, Wt);
        qkv_bf<<<dim3(4, 64, 3), 256, 0, stream>>>(Xbf, Wt, bq, bk, bv, Qh, Kh, VhT);
        flash_attn_f<<<dim3(512), 512, 0, stream>>>(Qh, Kh, VhT, Ao);
        out_gemm<<<dim3(4, 64), 256, 0, stream>>>(Ao, Wt + (size_t)3 * DM_ * DM_, bo, out);
    } else {
        unsigned short* Ao = tail;
        wtrans<<<dim3(8, 8, 4), 256, 0, stream>>>(Wq, Wk, Wv, Wo, Wt);
        qkv_proj<<<dim3(4, 64, 3), 256, 0, stream>>>(q, k, v, Wt, bq, bk, bv, Qh, Kh, VhT);
        flash_attn<<<dim3(512), 256, 0, stream>>>(Qh, Kh, VhT, Ao);
        out_gemm<<<dim3(4, 64), 256, 0, stream>>>(Ao, Wt + (size_t)3 * DM_ * DM_, bo, out);
    }
}